// Round 13
// baseline (769.979 us; speedup 1.0000x reference)
//
#include <hip/hip_runtime.h>
#include <cstddef>

#define N_NODES 20000
#define N_EDGES 320000
#define IN_CH   64
#define HID     512
#define G4      2048
#define BN_EPS  1e-5f
// gate order in gates buffer: [f | g | i | o]
#define F_OFF   0
#define G_OFF   512
#define I_OFF   1024
#define O_OFF   1536

typedef __attribute__((ext_vector_type(8))) __bf16 bf16x8;
typedef __attribute__((ext_vector_type(4))) float f32x4;

__device__ __forceinline__ float sigmoidf_(float x) {
  return 1.0f / (1.0f + expf(-x));
}

// fp32 -> bf16 (RNE)
__device__ __forceinline__ unsigned short f2b(float f) {
  unsigned int u = __float_as_uint(f);
  u += 0x7FFFu + ((u >> 16) & 1u);
  return (unsigned short)(u >> 16);
}
__device__ __forceinline__ float b2f(unsigned short u) {
  return __uint_as_float(((unsigned int)u) << 16);
}

__device__ __forceinline__ void gld_lds16(const unsigned short* g, unsigned short* l) {
  __builtin_amdgcn_global_load_lds(
      (const __attribute__((address_space(1))) unsigned int*)(const void*)g,
      (__attribute__((address_space(3))) unsigned int*)(void*)l, 16, 0, 0);
}

// ---------------- zero fill ----------------
__global__ __launch_bounds__(256) void zero_k(float* __restrict__ p, size_t n) {
  size_t i = ((size_t)blockIdx.x * 256 + threadIdx.x) * 4;
  if (i + 3 < n) {
    *(float4*)&p[i] = make_float4(0.f, 0.f, 0.f, 0.f);
  } else {
    for (; i < n; i++) p[i] = 0.f;
  }
}

// ---------------- batched transpose + cvt: 18 weight panels in ONE launch ----
// Wt[n*ldo + k] = bf16(W[k*ldw + n]); blockIdx.z selects descriptor.
// (R4/R5 lesson: gate-interleaved B + fused cell1 epilogue measured SLOWER --
// split-gate layout with variable-K early exit is the proven structure.)
struct TcvtDesc { const float* W; unsigned short* Wt; int K, NC, ldw, ldo; };
struct TcvtBatch { TcvtDesc d[18]; };

__global__ void tcvtb_k(TcvtBatch batch) {
  const TcvtDesc dd = batch.d[blockIdx.z];
  __shared__ float tile[32][33];
  const int n0 = blockIdx.x * 32, k0 = blockIdx.y * 32;
  if (n0 >= dd.NC || k0 >= dd.K) return;   // uniform per-block exit
  const int tx = threadIdx.x, ty = threadIdx.y;  // 32 x 8
  #pragma unroll
  for (int i = 0; i < 32; i += 8) {
    int k = k0 + ty + i, n = n0 + tx;
    tile[ty + i][tx] = (k < dd.K && n < dd.NC) ? dd.W[(size_t)k * dd.ldw + n] : 0.f;
  }
  __syncthreads();
  #pragma unroll
  for (int i = 0; i < 32; i += 8) {
    int n = n0 + ty + i, k = k0 + tx;
    if (n < dd.NC && k < dd.K) dd.Wt[(size_t)n * dd.ldo + k] = f2b(tile[tx][ty + i]);
  }
}

// ---------------- CSR build ----------------
__global__ __launch_bounds__(256) void hist_k(const int* __restrict__ dst,
                                              int* __restrict__ counts) {
  int e = blockIdx.x * 256 + threadIdx.x;
  if (e < N_EDGES) atomicAdd(&counts[dst[e]], 1);
}

// Hierarchical exclusive scan (R10: replaces single-block scan's ~440 serial
// barriers on one CU; worth ~47us end-to-end).
__global__ __launch_bounds__(128) void scan1_k(const int* __restrict__ counts,
                                               int* __restrict__ offsets,
                                               int* __restrict__ bsum, int n) {
  __shared__ int sh[128];
  const int b = blockIdx.x, t = threadIdx.x;
  const int i = b * 128 + t;
  const int v = (i < n) ? counts[i] : 0;
  sh[t] = v;
  __syncthreads();
  #pragma unroll
  for (int off = 1; off < 128; off <<= 1) {
    int u = (t >= off) ? sh[t - off] : 0;
    __syncthreads();
    sh[t] += u;
    __syncthreads();
  }
  if (i < n) offsets[i] = sh[t] - v;   // exclusive within block (no base yet)
  if (t == 127) bsum[b] = sh[127];
}

__global__ __launch_bounds__(128) void scan2_k(const int* __restrict__ bsum,
                                               int* __restrict__ offsets,
                                               int* __restrict__ pos,
                                               int n, int nb) {
  __shared__ int red[128];
  __shared__ int base_s;
  const int b = blockIdx.x, t = threadIdx.x;
  int part = 0;
  if (t < b) part += bsum[t];
  if (t + 128 < b) part += bsum[t + 128];
  red[t] = part;
  __syncthreads();
  if (t < 64) {
    int v = red[t] + red[t + 64];
    #pragma unroll
    for (int off = 32; off > 0; off >>= 1) v += __shfl_down(v, off);
    if (t == 0) base_s = v;
  }
  __syncthreads();
  const int i = b * 128 + t;
  if (i < n) {
    int off = base_s + offsets[i];
    offsets[i] = off;
    pos[i] = off;
  }
  if (b == nb - 1 && t == 0) offsets[n] = base_s + bsum[b];
}

__global__ __launch_bounds__(256) void fill_k(
    const int* __restrict__ src, const int* __restrict__ dst,
    const float* __restrict__ ew, int* __restrict__ pos,
    int* __restrict__ s_s, float* __restrict__ w_s) {
  int e = blockIdx.x * 256 + threadIdx.x;
  if (e >= N_EDGES) return;
  int p = atomicAdd(&pos[dst[e]], 1);
  s_s[p] = src[e];
  w_s[p] = ew[e];
}

// ---------------- L0 gather directly on f32 input: xg = bf16(S·x) ------------
// Reads x f32 (5MB, L3-resident). 4-way unrolled edge loop: 4 independent
// row loads in flight per iteration (latency-bound otherwise).
__global__ __launch_bounds__(64) void gather64_k(
    const float* __restrict__ x, const int* __restrict__ offsets,
    const int* __restrict__ s_s, const float* __restrict__ w_s,
    unsigned short* __restrict__ xg) {
  const int sub = threadIdx.x >> 4;
  const int cg  = threadIdx.x & 15;
  const int n   = blockIdx.x * 4 + sub;
  const int beg = offsets[n], end = offsets[n + 1];
  float4 acc = make_float4(0.f, 0.f, 0.f, 0.f);
  int i = beg;
  for (; i + 3 < end; i += 4) {
    const int   s0 = s_s[i],     s1 = s_s[i + 1];
    const int   s2 = s_s[i + 2], s3 = s_s[i + 3];
    const float w0 = w_s[i],     w1 = w_s[i + 1];
    const float w2 = w_s[i + 2], w3 = w_s[i + 3];
    const float4 v0 = *(const float4*)&x[(size_t)s0 * IN_CH + cg * 4];
    const float4 v1 = *(const float4*)&x[(size_t)s1 * IN_CH + cg * 4];
    const float4 v2 = *(const float4*)&x[(size_t)s2 * IN_CH + cg * 4];
    const float4 v3 = *(const float4*)&x[(size_t)s3 * IN_CH + cg * 4];
    acc.x = fmaf(w0, v0.x, acc.x); acc.y = fmaf(w0, v0.y, acc.y);
    acc.z = fmaf(w0, v0.z, acc.z); acc.w = fmaf(w0, v0.w, acc.w);
    acc.x = fmaf(w1, v1.x, acc.x); acc.y = fmaf(w1, v1.y, acc.y);
    acc.z = fmaf(w1, v1.z, acc.z); acc.w = fmaf(w1, v1.w, acc.w);
    acc.x = fmaf(w2, v2.x, acc.x); acc.y = fmaf(w2, v2.y, acc.y);
    acc.z = fmaf(w2, v2.z, acc.z); acc.w = fmaf(w2, v2.w, acc.w);
    acc.x = fmaf(w3, v3.x, acc.x); acc.y = fmaf(w3, v3.y, acc.y);
    acc.z = fmaf(w3, v3.z, acc.z); acc.w = fmaf(w3, v3.w, acc.w);
  }
  for (; i < end; i++) {
    const int   s = s_s[i];
    const float w = w_s[i];
    const float4 v = *(const float4*)&x[(size_t)s * IN_CH + cg * 4];
    acc.x = fmaf(w, v.x, acc.x);
    acc.y = fmaf(w, v.y, acc.y);
    acc.z = fmaf(w, v.z, acc.z);
    acc.w = fmaf(w, v.w, acc.w);
  }
  ushort4 o; o.x = f2b(acc.x); o.y = f2b(acc.y); o.z = f2b(acc.z); o.w = f2b(acc.w);
  *(ushort4*)&xg[(size_t)n * IN_CH + cg * 4] = o;
}

// ---------------- aggregation gather (bf16 XW -> bf16 H), 4-way pipelined ------
// ONE BLOCK PER NODE (20000 blocks). R9 lesson: grid-striding this kernel at
// 2048 blocks cut TLP 10x on a latency-bound access pattern -> 230us (5x
// regression). Max block count is the proven-fast shape; do not fuse stats in.
__global__ __launch_bounds__(128) void gather_k(
    const unsigned short* __restrict__ XW, const int* __restrict__ offsets,
    const int* __restrict__ s_s, const float* __restrict__ w_s,
    unsigned short* __restrict__ H) {
  const int n = blockIdx.x;
  const int t = threadIdx.x;
  const int beg = offsets[n], end = offsets[n + 1];
  float4 acc = make_float4(0.f, 0.f, 0.f, 0.f);
  int i = beg;
  for (; i + 3 < end; i += 4) {
    const int   s0 = s_s[i],     s1 = s_s[i + 1];
    const int   s2 = s_s[i + 2], s3 = s_s[i + 3];
    const float w0 = w_s[i],     w1 = w_s[i + 1];
    const float w2 = w_s[i + 2], w3 = w_s[i + 3];
    const ushort4 v0 = *(const ushort4*)&XW[(size_t)s0 * HID + t * 4];
    const ushort4 v1 = *(const ushort4*)&XW[(size_t)s1 * HID + t * 4];
    const ushort4 v2 = *(const ushort4*)&XW[(size_t)s2 * HID + t * 4];
    const ushort4 v3 = *(const ushort4*)&XW[(size_t)s3 * HID + t * 4];
    acc.x = fmaf(w0, b2f(v0.x), acc.x); acc.y = fmaf(w0, b2f(v0.y), acc.y);
    acc.z = fmaf(w0, b2f(v0.z), acc.z); acc.w = fmaf(w0, b2f(v0.w), acc.w);
    acc.x = fmaf(w1, b2f(v1.x), acc.x); acc.y = fmaf(w1, b2f(v1.y), acc.y);
    acc.z = fmaf(w1, b2f(v1.z), acc.z); acc.w = fmaf(w1, b2f(v1.w), acc.w);
    acc.x = fmaf(w2, b2f(v2.x), acc.x); acc.y = fmaf(w2, b2f(v2.y), acc.y);
    acc.z = fmaf(w2, b2f(v2.z), acc.z); acc.w = fmaf(w2, b2f(v2.w), acc.w);
    acc.x = fmaf(w3, b2f(v3.x), acc.x); acc.y = fmaf(w3, b2f(v3.y), acc.y);
    acc.z = fmaf(w3, b2f(v3.z), acc.z); acc.w = fmaf(w3, b2f(v3.w), acc.w);
  }
  for (; i < end; i++) {
    const int   s = s_s[i];
    const float w = w_s[i];
    const ushort4 v = *(const ushort4*)&XW[(size_t)s * HID + t * 4];
    acc.x = fmaf(w, b2f(v.x), acc.x);
    acc.y = fmaf(w, b2f(v.y), acc.y);
    acc.z = fmaf(w, b2f(v.z), acc.z);
    acc.w = fmaf(w, b2f(v.w), acc.w);
  }
  ushort4 o; o.x = f2b(acc.x); o.y = f2b(acc.y); o.z = f2b(acc.z); o.w = f2b(acc.w);
  *(ushort4*)&H[(size_t)n * HID + t * 4] = o;
}

// ---------------- BN stats over bf16 H ----------------
__global__ __launch_bounds__(256) void bn_stats_k(
    const unsigned short* __restrict__ H, float* __restrict__ stats, int N)
{
  const int tx = threadIdx.x & 63;
  const int ty = threadIdx.x >> 6;
  const int col = blockIdx.x * 64 + tx;
  float s1 = 0.f, s2 = 0.f;
  for (int r = blockIdx.y * 4 + ty; r < N; r += gridDim.y * 4) {
    float v = b2f(H[(size_t)r * HID + col]);
    s1 += v; s2 += v * v;
  }
  __shared__ float red[2][4][64];
  red[0][ty][tx] = s1;
  red[1][ty][tx] = s2;
  __syncthreads();
  if (ty == 0) {
    s1 = red[0][0][tx] + red[0][1][tx] + red[0][2][tx] + red[0][3][tx];
    s2 = red[1][0][tx] + red[1][1][tx] + red[1][2][tx] + red[1][3][tx];
    atomicAdd(&stats[col], s1);
    atomicAdd(&stats[HID + col], s2);
  }
}

// ---------------- BN apply + ReLU: bf16 H -> bf16 h ----------------
__global__ __launch_bounds__(256) void bn_apply_k(
    const unsigned short* __restrict__ H, const float* __restrict__ stats,
    const float* __restrict__ gamma, const float* __restrict__ beta,
    unsigned short* __restrict__ out, int N)
{
  size_t gid = (size_t)blockIdx.x * 256 + threadIdx.x;
  size_t idx = gid * 4;
  if (idx >= (size_t)N * HID) return;
  int col = (int)(idx & (HID - 1));
  const ushort4 v = *(const ushort4*)&H[idx];
  float r[4] = {b2f(v.x), b2f(v.y), b2f(v.z), b2f(v.w)};
  ushort4 o;
  unsigned short* op = &o.x;
  #pragma unroll
  for (int i = 0; i < 4; i++) {
    int c = col + i;
    float mean = stats[c] * (1.0f / N);
    float var  = stats[HID + c] * (1.0f / N) - mean * mean;
    float scale = gamma[c] / sqrtf(var + BN_EPS);
    float shift = beta[c] - mean * scale;
    op[i] = f2b(fmaxf(fmaf(r[i], scale, shift), 0.0f));
  }
  *(ushort4*)&out[idx] = o;
}

// ---------------- bf16 MFMA GEMM, BK=64, swizzled LDS + XCD mapping ----
// C(f32) or C16(bf16) [M,NC] (+)= A[M,K] * Bt[NC,K]^T (+bias)
// R6/R8-proven depth-1 double-buffer. Scheduling ledger (do not revisit):
//   BK=32 4-deep + sched_barrier pins: 95->117us (R2)
//   counted vmcnt(6) 3-buffer 72KB: 96->122us, FETCH 113->227MB (R7)
//   gate-interleaved fused-cell1: +25% structurally (R4/R5)
// R13: BN=256 instantiation for the wide gates GEMMs -- at M=20000 the
// A-panels no longer cache across ncolb=16 col-blocks (FETCH 360MB vs 67MB
// ideal, fetch-bound); BN=256 halves ncolb -> halves A re-reads. Waves 2x2,
// each 32rx128c (MI=2, NI=8); LDS 80KB -> 2 blk/CU (R1: perf-equal).
// Variable-K boundary (col 1024) aligns with BN=256 blocks exactly.
// ntc=1: non-temporal stores for write-once/read-once outputs (R8/R11).
// Swizzle: row r's chunk c at slot (c+r)&7 -> 2-way bank aliasing (free).
template<int BM, int BN>
__global__ __launch_bounds__(256) void gemm_bf16_k(
    const unsigned short* __restrict__ A, int lda,
    const unsigned short* __restrict__ A2, int lda2, int ksplit,
    const unsigned short* __restrict__ Bt,
    float* __restrict__ C, unsigned short* __restrict__ C16,
    const float* __restrict__ bias,
    int M, int K, int Ksmall, int NC, int ldc, int acc, int ntc,
    int nrowb, int ncolb)
{
  const int b   = blockIdx.x;
  const int xcd = b & 7;
  const int j   = b >> 3;
  const int col_b = j % ncolb;
  const int row_b = (j / ncolb) * 8 + xcd;
  if (row_b >= nrowb) return;

  constexpr int MI  = 2;
  constexpr int NI  = (BN == 256) ? 8 : 4;
  constexpr int ASZ = BM * 64;
  constexpr int BSZ = BN * 64;
  __shared__ unsigned short As[2 * ASZ];
  __shared__ unsigned short Bs[2 * BSZ];
  const int row0 = row_b * BM;
  const int col0 = col_b * BN;
  const int Kthis = (col0 < 1024) ? K : Ksmall;
  const int t    = threadIdx.x;
  const int lane = t & 63;
  const int w    = t >> 6;
  const int wro  = (BN >= 128) ? (w >> 1) * 32 : w * 32;
  const int wco  = (BN >= 128) ? (w & 1) * (BN / 2) : 0;
  const int q    = lane >> 4;
  const int l16  = lane & 15;

  f32x4 accr[MI][NI] = {};

  auto stage = [&](int buf, int k0) {
    unsigned short* Ad = As + buf * ASZ;
    unsigned short* Bd = Bs + buf * BSZ;
    #pragma unroll
    for (int i = 0; i < BM / 32; i++) {
      int s  = t + i * 256;
      int r  = s >> 3, cq = s & 7;
      int kq = (cq - r) & 7;
      int gr = row0 + r; if (gr > M - 1) gr = M - 1;
      int kk = k0 + kq * 8;
      const unsigned short* bp = (kk < ksplit) ? A : A2;
      size_t off = (kk < ksplit) ? ((size_t)gr * lda + kk)
                                 : ((size_t)gr * lda2 + (kk - ksplit));
      gld_lds16(bp + off, Ad + (size_t)s * 8);
    }
    #pragma unroll
    for (int i = 0; i < BN / 32; i++) {
      int s  = t + i * 256;
      int r  = s >> 3, cq = s & 7;
      int kq = (cq - r) & 7;
      gld_lds16(Bt + (size_t)(col0 + r) * K + k0 + kq * 8, Bd + (size_t)s * 8);
    }
  };

  stage(0, 0);
  int cur = 0;
  for (int k0 = 0; k0 < Kthis; k0 += 64) {
    __syncthreads();
    if (k0 + 64 < Kthis) stage(cur ^ 1, k0 + 64);

    const unsigned short* Ac = As + cur * ASZ;
    const unsigned short* Bc = Bs + cur * BSZ;
    #pragma unroll
    for (int ks = 0; ks < 2; ks++) {
      bf16x8 af[MI], bfr[NI];
      #pragma unroll
      for (int mi = 0; mi < MI; mi++) {
        int r = wro + mi * 16 + l16;
        int slot = (ks * 4 + q + r) & 7;
        af[mi] = *(const bf16x8*)&Ac[r * 64 + slot * 8];
      }
      #pragma unroll
      for (int ni = 0; ni < NI; ni++) {
        int r = wco + ni * 16 + l16;
        int slot = (ks * 4 + q + r) & 7;
        bfr[ni] = *(const bf16x8*)&Bc[r * 64 + slot * 8];
      }
      #pragma unroll
      for (int mi = 0; mi < MI; mi++)
        #pragma unroll
        for (int ni = 0; ni < NI; ni++)
          accr[mi][ni] = __builtin_amdgcn_mfma_f32_16x16x32_bf16(
              af[mi], bfr[ni], accr[mi][ni], 0, 0, 0);
    }
    cur ^= 1;
  }

  #pragma unroll
  for (int mi = 0; mi < MI; mi++) {
    #pragma unroll
    for (int ni = 0; ni < NI; ni++) {
      int col = col0 + wco + ni * 16 + l16;
      #pragma unroll
      for (int r = 0; r < 4; r++) {
        int row = row0 + wro + mi * 16 + q * 4 + r;
        if (row < M) {
          float v = accr[mi][ni][r];
          if (C16) {
            unsigned short hv = f2b(v);
            unsigned short* hp = &C16[(size_t)row * ldc + col];
            if (ntc) __builtin_nontemporal_store(hv, hp);
            else     *hp = hv;
          } else {
            float* cp = &C[(size_t)row * ldc + col];
            if (acc)       *cp += v;
            else if (bias) *cp  = v + bias[col];
            else if (ntc)  __builtin_nontemporal_store(v, cp);
            else           *cp  = v;
          }
        }
      }
    }
  }
}

// ---------------- LSTM cell part 1 (gate order f|g|i|o; bias added here) --------
// R11/R12: gates bf16; c state kept ONLY as bf16 in a16[:,512:] (fp32 cbuf
// eliminated -- frees bufH for a16 so CH doubles). cin16 = prev c (bf16).
__global__ __launch_bounds__(256) void cell1_k(
    const unsigned short* __restrict__ gates, const float* __restrict__ lb,
    const unsigned short* __restrict__ cin16, int ldc16,
    unsigned short* __restrict__ cout16, int ld16,
    int rows, int hasC)
{
  size_t gid = (size_t)blockIdx.x * 256 + threadIdx.x;
  if (gid >= (size_t)rows * HID) return;
  size_t row = gid >> 9;
  int    col = (int)(gid & (HID - 1));
  const unsigned short* g = &gates[row * G4];
  float ig = sigmoidf_(b2f(__builtin_nontemporal_load(&g[I_OFF + col])) + lb[col]);
  float gg = tanhf(b2f(__builtin_nontemporal_load(&g[G_OFF + col])) + lb[2 * HID + col]);
  float c;
  if (hasC) {
    float fg = sigmoidf_(b2f(__builtin_nontemporal_load(&g[F_OFF + col])) + lb[HID + col]);
    c = fg * b2f(cin16[row * ldc16 + col]) + ig * gg;
  } else {
    c = ig * gg;
  }
  cout16[row * ld16 + col] = f2b(c);
}

// ---------------- LSTM cell part 2: hy16 = sigma(gates_O + obuf + b_o)*tanh(c) ---
__global__ __launch_bounds__(256) void cell2_k(
    const unsigned short* __restrict__ gates, const unsigned short* __restrict__ obuf16,
    const float* __restrict__ lb, const unsigned short* __restrict__ cy16, int ldcy,
    unsigned short* __restrict__ hy16, int ld16, int rows)
{
  size_t gid = (size_t)blockIdx.x * 256 + threadIdx.x;
  if (gid >= (size_t)rows * HID) return;
  size_t row = gid >> 9;
  int    col = (int)(gid & (HID - 1));
  float ov = b2f(__builtin_nontemporal_load(&gates[row * G4 + O_OFF + col]));
  float og = sigmoidf_(ov + b2f(obuf16[row * HID + col]) + lb[3 * HID + col]);
  float h = og * tanhf(b2f(cy16[row * ldcy + col]));
  hy16[row * ld16 + col] = f2b(h);
}

// ---------------- fused final cell2 + output projection ----------------
__global__ __launch_bounds__(256) void cellout_k(
    const unsigned short* __restrict__ gates, const unsigned short* __restrict__ obuf16,
    const float* __restrict__ lb, const unsigned short* __restrict__ cy16, int ldcy,
    const float* __restrict__ W, const float* __restrict__ b,
    float* __restrict__ out, int rows)
{
  int wave = (int)(((size_t)blockIdx.x * 256 + threadIdx.x) >> 6);
  int lane = threadIdx.x & 63;
  if (wave >= rows) return;
  const unsigned short* g  = &gates[(size_t)wave * G4 + O_OFF];
  const unsigned short* ob = &obuf16[(size_t)wave * HID];
  const unsigned short* cr = &cy16[(size_t)wave * ldcy];
  float hy[8];
  #pragma unroll
  for (int j = 0; j < 8; j++) {
    int k = lane + j * 64;
    float og = sigmoidf_(b2f(__builtin_nontemporal_load(&g[k])) + b2f(ob[k]) + lb[3 * HID + k]);
    hy[j] = og * tanhf(b2f(cr[k]));
  }
  float acc[12] = {};
  #pragma unroll
  for (int j = 0; j < 8; j++) {
    int k = lane + j * 64;
    const float* wr = &W[k * 12];
    #pragma unroll
    for (int p = 0; p < 12; p++) acc[p] = fmaf(hy[j], wr[p], acc[p]);
  }
  #pragma unroll
  for (int p = 0; p < 12; p++) {
    float v = acc[p];
    #pragma unroll
    for (int off = 32; off > 0; off >>= 1) v += __shfl_down(v, off);
    if (lane == 0) out[(size_t)wave * 12 + p] = v + b[p];
  }
}

extern "C" void kernel_launch(void* const* d_in, const int* in_sizes, int n_in,
                              void* d_out, int out_size, void* d_ws, size_t ws_size,
                              hipStream_t stream) {
  const float* x     = (const float*)d_in[0];
  const int*   ei    = (const int*)d_in[1];
  const float* ew    = (const float*)d_in[2];
  const float* gcn0W = (const float*)d_in[3];
  const float* gcnW  = (const float*)d_in[5];
  const float* gamma = (const float*)d_in[7];
  const float* beta  = (const float*)d_in[8];
  const float* wih   = (const float*)d_in[9];
  const float* whh   = (const float*)d_in[10];
  const float* wch   = (const float*)d_in[11];
  const float* lstmb = (const float*)d_in[12];
  const float* outW  = (const float*)d_in[13];
  const float* outb  = (const float*)d_in[14];
  float* out = (float*)d_out;

  const int* src = ei;
  const int* dst = ei + N_EDGES;

  // R12: gates are bf16 -> half the bytes per row -> CH doubles within the
  // SAME workspace region the fp32 layout used (byte-exact fit).
  const int CHL = (ws_size >= (size_t)215000000) ? 10000 : 5000;  // layout unit
  const int CH  = 2 * CHL;
  const int NCHUNK = N_NODES / CH;

  // -------- workspace layout (byte offsets identical to R11) --------
  const size_t NH = (size_t)N_NODES * HID;
  float* ws = (float*)d_ws;
  float* gates = ws;                                 // CHL*2048 fp32 bytes = CH*2048 bf16
  float* bufH  = gates + (size_t)CHL * G4;           // NH fp32 (GCN H / LSTM a16)
  unsigned short* hbA16 = (unsigned short*)(bufH + NH);
  unsigned short* hbB16 = hbA16 + NH;                // GCN scratch / LSTM obuf16
  unsigned short* x16   = hbB16 + NH;                // scratch (scan block sums)
  unsigned short* g0t   = x16 + (size_t)N_NODES * IN_CH;
  unsigned short* g1t   = g0t   + 512 * 64;
  unsigned short* g2t   = g1t   + 512 * 512;
  unsigned short* wih0t = g2t   + 512 * 512;             // [1536,512] rows g|i|o
  unsigned short* wcat3 = wih0t + (size_t)1536 * 512;    // [2048,1536] fused L1 B
  unsigned short* wch0ot= wcat3 + (size_t)2048 * 1536;   // [512,512]
  unsigned short* wch1ot= wch0ot + 512 * 512;            // [512,512]
  unsigned short* wend  = wch1ot + 512 * 512;
  float* stats = (float*)wend;                       // 3 layers x 1024 floats
  int*   csr   = (int*)(stats + 3072);
  int*   counts  = csr;
  int*   offsets = csr + 20032;
  int*   cpos    = csr + 40064;
  int*   s_s     = csr + 60096;
  float* w_s     = (float*)(csr + 380096);
  int*   bsum    = (int*)x16;                        // 157 ints, prologue-only

  unsigned short* bufH16 = (unsigned short*)bufH;  // bf16 H during GCN
  // LSTM-phase buffers (GCN scratch reused; no temporal overlap):
  unsigned short* gates16 = (unsigned short*)gates;  // bf16 [CH, G4]
  unsigned short* a16     = (unsigned short*)bufH;   // bf16 [CH,1024] = [hy | c]
  unsigned short* obuf16  = hbB16;                   // bf16 [CH,512] o-peephole

  const dim3 blk(256);
  auto gemm256 = [&](const unsigned short* A, int lda,
                     const unsigned short* A2, int lda2, int ksplit,
                     const unsigned short* Bt, unsigned short* C16,
                     int M, int K, int Ksmall, int NC, int ldc) {
    int nrowb = (M + 63) / 64;
    int ncolb = NC / 256;
    int nblocks = 8 * ((nrowb + 7) / 8) * ncolb;
    hipLaunchKernelGGL((gemm_bf16_k<64, 256>), dim3(nblocks), blk, 0, stream,
                       A, lda, A2, lda2, ksplit, Bt, (float*)nullptr, C16,
                       (const float*)nullptr,
                       M, K, Ksmall, NC, ldc, 0, /*ntc=*/1, nrowb, ncolb);
  };
  auto gemm64 = [&](const unsigned short* A, int lda,
                    const unsigned short* Bt, float* C, unsigned short* C16,
                    const float* bias, int M, int K, int NC, int ldc, int acc) {
    int nrowb = (M + 127) / 128;
    int ncolb = NC / 64;
    int nblocks = 8 * ((nrowb + 7) / 8) * ncolb;
    hipLaunchKernelGGL((gemm_bf16_k<128, 64>), dim3(nblocks), blk, 0, stream,
                       A, lda, A, lda, K, Bt, C, C16, bias,
                       M, K, K, NC, ldc, acc, /*ntc=*/0, nrowb, ncolb);
  };
  auto zero = [&](float* p, size_t n) {
    hipLaunchKernelGGL(zero_k, dim3((unsigned)((n / 4 + 255) / 256)), blk, 0, stream, p, n);
  };

  // -------- weight prep: all 18 transposes in ONE launch --------
  const float* wih1 = wih + (size_t)HID * G4;
  const float* whh1 = whh + (size_t)HID * G4;
  const float* wch1 = wch + (size_t)HID * 3 * HID;
  {
    TcvtBatch tb;
    int n = 0;
    auto add = [&](const float* W, unsigned short* Wt, int K, int NC, int ldw, int ldo) {
      tb.d[n++] = TcvtDesc{W, Wt, K, NC, ldw, ldo};
    };
    add(gcn0W, g0t, IN_CH, HID, HID, IN_CH);
    add(gcnW,                     g1t, HID, HID, HID, HID);
    add(gcnW + (size_t)HID * HID, g2t, HID, HID, HID, HID);
    // layer-0 Wih rows [g|i|o] (f dead: c=0)
    add(wih + 2 * HID, wih0t,                      HID, HID, G4, HID);  // g
    add(wih,           wih0t + (size_t)512 * 512,  HID, HID, G4, HID);  // i
    add(wih + 3 * HID, wih0t + (size_t)1024 * 512, HID, HID, G4, HID);  // o
    // fused layer-1 B [2048 x 1536]: rows f,g K=1536 (ih|hh|peep); i,o K=1024
    add(wih1 + HID,     wcat3 + (size_t)F_OFF * 1536,        HID, HID, G4, 1536);
    add(whh1 + HID,     wcat3 + (size_t)F_OFF * 1536 + 512,  HID, HID, G4, 1536);
    add(wch1 + HID,     wcat3 + (size_t)F_OFF * 1536 + 1024, HID, HID, 3 * HID, 1536);
    add(wih1 + 2 * HID, wcat3 + (size_t)G_OFF * 1536,        HID, HID, G4, 1536);
    add(whh1 + 2 * HID, wcat3 + (size_t)G_OFF * 1536 + 512,  HID, HID, G4, 1536);
    add(wch1,           wcat3 + (size_t)G_OFF * 1536 + 1024, HID, HID, 3 * HID, 1536);
    add(wih1,           wcat3 + (size_t)I_OFF * 1536,        HID, HID, G4, 1536);
    add(whh1,           wcat3 + (size_t)I_OFF * 1536 + 512,  HID, HID, G4, 1536);
    add(wih1 + 3 * HID, wcat3 + (size_t)O_OFF * 1536,        HID, HID, G4, 1536);
    add(whh1 + 3 * HID, wcat3 + (size_t)O_OFF * 1536 + 512,  HID, HID, G4, 1536);
    add(wch + 2 * HID,  wch0ot, HID, HID, 3 * HID, HID);   // Wch0 o-peephole
    add(wch1 + 2 * HID, wch1ot, HID, HID, 3 * HID, HID);   // Wch1 o-peephole
    hipLaunchKernelGGL(tcvtb_k, dim3(16, 16, 18), dim3(32, 8), 0, stream, tb);
  }

  // -------- CSR build; stats+counts zeroed in ONE launch (contiguous) --------
  const int e_blocks = (N_EDGES + 255) / 256;
  const int nscanb = (N_NODES + 127) / 128;   // 157
  zero(stats, 3 * 1024 + N_NODES);            // covers stats AND counts
  hipLaunchKernelGGL(hist_k, dim3(e_blocks), blk, 0, stream, dst, counts);
  hipLaunchKernelGGL(scan1_k, dim3(nscanb), dim3(128), 0, stream,
                     counts, offsets, bsum, N_NODES);
  hipLaunchKernelGGL(scan2_k, dim3(nscanb), dim3(128), 0, stream,
                     bsum, offsets, cpos, N_NODES, nscanb);
  hipLaunchKernelGGL(fill_k, dim3(e_blocks), blk, 0, stream, src, dst, ew, cpos, s_s, w_s);

  // -------- GCN layer 0: gather-first (linearity), direct f32 input --------
  hipLaunchKernelGGL(gather64_k, dim3(N_NODES / 4), dim3(64), 0, stream,
                     x, offsets, s_s, w_s, hbB16);
  gemm64(hbB16, IN_CH, g0t, nullptr, bufH16, nullptr, N_NODES, IN_CH, HID, HID, 0);
  hipLaunchKernelGGL(bn_stats_k, dim3(8, 64), blk, 0, stream, bufH16, stats, N_NODES);
  hipLaunchKernelGGL(bn_apply_k, dim3((unsigned)(NH / 4 / 256)), blk, 0, stream,
                     bufH16, stats, gamma, beta, hbA16, N_NODES);

  // -------- GCN layers 1,2: GEMM -> gather -> BN stats -> BN apply --------
  const unsigned short* gWt2[2] = {g1t, g2t};
  const unsigned short* gA2[2]  = {hbA16, hbB16};
  unsigned short*       gXW2[2] = {hbB16, hbA16};
  unsigned short*       gO2[2]  = {hbB16, hbA16};
  for (int l = 0; l < 2; l++) {
    gemm64(gA2[l], HID, gWt2[l], nullptr, gXW2[l], nullptr, N_NODES, HID, HID, HID, 0);
    hipLaunchKernelGGL(gather_k, dim3(N_NODES), dim3(128), 0, stream,
                       gXW2[l], offsets, s_s, w_s, bufH16);
    hipLaunchKernelGGL(bn_stats_k, dim3(8, 64), blk, 0, stream, bufH16,
                       stats + (l + 1) * 1024, N_NODES);
    hipLaunchKernelGGL(bn_apply_k, dim3((unsigned)(NH / 4 / 256)), blk, 0, stream,
                       bufH16, stats + (l + 1) * 1024, gamma + (l + 1) * HID,
                       beta + (l + 1) * HID, gO2[l], N_NODES);
  }
  unsigned short* hfin16 = hbA16;
  // After GCN: hbB16 (layer-1 h) and bufH (pre-BN H) are dead -> reuse as
  // obuf16 and a16 for the LSTM phase. hfin16=hbA16 preserved.

  // -------- LSTM + output, chunked (CH doubled vs R11; often NCHUNK=1) ------
  for (int ci = 0; ci < NCHUNK; ci++) {
    const int r0 = ci * CH;
    const unsigned short* h_c = hfin16 + (size_t)r0 * HID;
    const int cell_blocks = (int)(((size_t)CH * HID + 255) / 256);

    // layer 0 (h=c=0, f dead): gates16[G|I|O] = bf16(h @ Wih0_gio), nt stores
    // NC=1536 = 6 x 256-col blocks; K uniform 512.
    gemm256(h_c, HID, h_c, HID, HID, wih0t, gates16 + G_OFF,
            CH, HID, HID, 1536, G4);
    // c0 -> a16[:,512:] bf16
    hipLaunchKernelGGL(cell1_k, dim3(cell_blocks), blk, 0, stream,
                       gates16, lstmb, (const unsigned short*)nullptr, 0,
                       a16 + 512, 1024, CH, 0);
    // o peephole L0: obuf16 = bf16(c0 @ Wch0_o)
    gemm64(a16 + 512, 1024, wch0ot, nullptr, obuf16, nullptr, CH, HID, HID, HID, 0);
    // hy0 -> a16[:,0:512] bf16
    hipLaunchKernelGGL(cell2_k, dim3(cell_blocks), blk, 0, stream,
                       gates16, obuf16, lstmb, a16 + 512, 1024, a16, 1024, CH);

    // layer 1 fused: gates16 = bf16([h | hy0 | c0] @ wcat3) (split-A;
    // f,g K=1536 [col blocks 0-3], i,o K=1024 [blocks 4-7]), nt stores
    gemm256(h_c, HID, a16, 1024, HID, wcat3, gates16,
            CH, 1536, 1024, G4, G4);
    // c1 -> a16[:,512:] (reads c0 from same slot elementwise-before-write)
    hipLaunchKernelGGL(cell1_k, dim3(cell_blocks), blk, 0, stream,
                       gates16, lstmb + G4, a16 + 512, 1024,
                       a16 + 512, 1024, CH, 1);
    // o peephole L1: obuf16 = bf16(c1 @ Wch1_o)
    gemm64(a16 + 512, 1024, wch1ot, nullptr, obuf16, nullptr, CH, HID, HID, HID, 0);
    // fused cell2 + output projection
    hipLaunchKernelGGL(cellout_k, dim3((CH * 64 + 255) / 256), blk, 0, stream,
                       gates16, obuf16, lstmb + G4, a16 + 512, 1024, outW, outb,
                       out + (size_t)r0 * 12, CH);
  }
}

// Round 14
// 751.196 us; speedup vs baseline: 1.0250x; 1.0250x over previous
//
#include <hip/hip_runtime.h>
#include <cstddef>

#define N_NODES 20000
#define N_EDGES 320000
#define IN_CH   64
#define HID     512
#define G4      2048
#define BN_EPS  1e-5f
// gate order in gates buffer: [f | g | i | o]
#define F_OFF   0
#define G_OFF   512
#define I_OFF   1024
#define O_OFF   1536

typedef __attribute__((ext_vector_type(8))) __bf16 bf16x8;
typedef __attribute__((ext_vector_type(4))) float f32x4;

__device__ __forceinline__ float sigmoidf_(float x) {
  return 1.0f / (1.0f + expf(-x));
}

// fp32 -> bf16 (RNE)
__device__ __forceinline__ unsigned short f2b(float f) {
  unsigned int u = __float_as_uint(f);
  u += 0x7FFFu + ((u >> 16) & 1u);
  return (unsigned short)(u >> 16);
}
__device__ __forceinline__ float b2f(unsigned short u) {
  return __uint_as_float(((unsigned int)u) << 16);
}

__device__ __forceinline__ void gld_lds16(const unsigned short* g, unsigned short* l) {
  __builtin_amdgcn_global_load_lds(
      (const __attribute__((address_space(1))) unsigned int*)(const void*)g,
      (__attribute__((address_space(3))) unsigned int*)(void*)l, 16, 0, 0);
}

// ---------------- zero fill ----------------
__global__ __launch_bounds__(256) void zero_k(float* __restrict__ p, size_t n) {
  size_t i = ((size_t)blockIdx.x * 256 + threadIdx.x) * 4;
  if (i + 3 < n) {
    *(float4*)&p[i] = make_float4(0.f, 0.f, 0.f, 0.f);
  } else {
    for (; i < n; i++) p[i] = 0.f;
  }
}

// ---------------- batched transpose + cvt: 18 weight panels in ONE launch ----
// Wt[n*ldo + k] = bf16(W[k*ldw + n]); blockIdx.z selects descriptor.
// (R4/R5 lesson: gate-interleaved B + fused cell1 epilogue measured SLOWER --
// split-gate layout with variable-K early exit is the proven structure.)
struct TcvtDesc { const float* W; unsigned short* Wt; int K, NC, ldw, ldo; };
struct TcvtBatch { TcvtDesc d[18]; };

__global__ void tcvtb_k(TcvtBatch batch) {
  const TcvtDesc dd = batch.d[blockIdx.z];
  __shared__ float tile[32][33];
  const int n0 = blockIdx.x * 32, k0 = blockIdx.y * 32;
  if (n0 >= dd.NC || k0 >= dd.K) return;   // uniform per-block exit
  const int tx = threadIdx.x, ty = threadIdx.y;  // 32 x 8
  #pragma unroll
  for (int i = 0; i < 32; i += 8) {
    int k = k0 + ty + i, n = n0 + tx;
    tile[ty + i][tx] = (k < dd.K && n < dd.NC) ? dd.W[(size_t)k * dd.ldw + n] : 0.f;
  }
  __syncthreads();
  #pragma unroll
  for (int i = 0; i < 32; i += 8) {
    int n = n0 + ty + i, k = k0 + tx;
    if (n < dd.NC && k < dd.K) dd.Wt[(size_t)n * dd.ldo + k] = f2b(tile[tx][ty + i]);
  }
}

// ---------------- CSR build ----------------
__global__ __launch_bounds__(256) void hist_k(const int* __restrict__ dst,
                                              int* __restrict__ counts) {
  int e = blockIdx.x * 256 + threadIdx.x;
  if (e < N_EDGES) atomicAdd(&counts[dst[e]], 1);
}

// Hierarchical exclusive scan (R10: replaces single-block scan's ~440 serial
// barriers on one CU; worth ~47us end-to-end).
__global__ __launch_bounds__(128) void scan1_k(const int* __restrict__ counts,
                                               int* __restrict__ offsets,
                                               int* __restrict__ bsum, int n) {
  __shared__ int sh[128];
  const int b = blockIdx.x, t = threadIdx.x;
  const int i = b * 128 + t;
  const int v = (i < n) ? counts[i] : 0;
  sh[t] = v;
  __syncthreads();
  #pragma unroll
  for (int off = 1; off < 128; off <<= 1) {
    int u = (t >= off) ? sh[t - off] : 0;
    __syncthreads();
    sh[t] += u;
    __syncthreads();
  }
  if (i < n) offsets[i] = sh[t] - v;   // exclusive within block (no base yet)
  if (t == 127) bsum[b] = sh[127];
}

__global__ __launch_bounds__(128) void scan2_k(const int* __restrict__ bsum,
                                               int* __restrict__ offsets,
                                               int* __restrict__ pos,
                                               int n, int nb) {
  __shared__ int red[128];
  __shared__ int base_s;
  const int b = blockIdx.x, t = threadIdx.x;
  int part = 0;
  if (t < b) part += bsum[t];
  if (t + 128 < b) part += bsum[t + 128];
  red[t] = part;
  __syncthreads();
  if (t < 64) {
    int v = red[t] + red[t + 64];
    #pragma unroll
    for (int off = 32; off > 0; off >>= 1) v += __shfl_down(v, off);
    if (t == 0) base_s = v;
  }
  __syncthreads();
  const int i = b * 128 + t;
  if (i < n) {
    int off = base_s + offsets[i];
    offsets[i] = off;
    pos[i] = off;
  }
  if (b == nb - 1 && t == 0) offsets[n] = base_s + bsum[b];
}

__global__ __launch_bounds__(256) void fill_k(
    const int* __restrict__ src, const int* __restrict__ dst,
    const float* __restrict__ ew, int* __restrict__ pos,
    int* __restrict__ s_s, float* __restrict__ w_s) {
  int e = blockIdx.x * 256 + threadIdx.x;
  if (e >= N_EDGES) return;
  int p = atomicAdd(&pos[dst[e]], 1);
  s_s[p] = src[e];
  w_s[p] = ew[e];
}

// ---------------- L0 gather directly on f32 input: xg = bf16(S·x) ------------
// Reads x f32 (5MB, L3-resident). 4-way unrolled edge loop: 4 independent
// row loads in flight per iteration (latency-bound otherwise).
__global__ __launch_bounds__(64) void gather64_k(
    const float* __restrict__ x, const int* __restrict__ offsets,
    const int* __restrict__ s_s, const float* __restrict__ w_s,
    unsigned short* __restrict__ xg) {
  const int sub = threadIdx.x >> 4;
  const int cg  = threadIdx.x & 15;
  const int n   = blockIdx.x * 4 + sub;
  const int beg = offsets[n], end = offsets[n + 1];
  float4 acc = make_float4(0.f, 0.f, 0.f, 0.f);
  int i = beg;
  for (; i + 3 < end; i += 4) {
    const int   s0 = s_s[i],     s1 = s_s[i + 1];
    const int   s2 = s_s[i + 2], s3 = s_s[i + 3];
    const float w0 = w_s[i],     w1 = w_s[i + 1];
    const float w2 = w_s[i + 2], w3 = w_s[i + 3];
    const float4 v0 = *(const float4*)&x[(size_t)s0 * IN_CH + cg * 4];
    const float4 v1 = *(const float4*)&x[(size_t)s1 * IN_CH + cg * 4];
    const float4 v2 = *(const float4*)&x[(size_t)s2 * IN_CH + cg * 4];
    const float4 v3 = *(const float4*)&x[(size_t)s3 * IN_CH + cg * 4];
    acc.x = fmaf(w0, v0.x, acc.x); acc.y = fmaf(w0, v0.y, acc.y);
    acc.z = fmaf(w0, v0.z, acc.z); acc.w = fmaf(w0, v0.w, acc.w);
    acc.x = fmaf(w1, v1.x, acc.x); acc.y = fmaf(w1, v1.y, acc.y);
    acc.z = fmaf(w1, v1.z, acc.z); acc.w = fmaf(w1, v1.w, acc.w);
    acc.x = fmaf(w2, v2.x, acc.x); acc.y = fmaf(w2, v2.y, acc.y);
    acc.z = fmaf(w2, v2.z, acc.z); acc.w = fmaf(w2, v2.w, acc.w);
    acc.x = fmaf(w3, v3.x, acc.x); acc.y = fmaf(w3, v3.y, acc.y);
    acc.z = fmaf(w3, v3.z, acc.z); acc.w = fmaf(w3, v3.w, acc.w);
  }
  for (; i < end; i++) {
    const int   s = s_s[i];
    const float w = w_s[i];
    const float4 v = *(const float4*)&x[(size_t)s * IN_CH + cg * 4];
    acc.x = fmaf(w, v.x, acc.x);
    acc.y = fmaf(w, v.y, acc.y);
    acc.z = fmaf(w, v.z, acc.z);
    acc.w = fmaf(w, v.w, acc.w);
  }
  ushort4 o; o.x = f2b(acc.x); o.y = f2b(acc.y); o.z = f2b(acc.z); o.w = f2b(acc.w);
  *(ushort4*)&xg[(size_t)n * IN_CH + cg * 4] = o;
}

// ---------------- aggregation gather (bf16 XW -> bf16 H), 4-way pipelined ------
// ONE BLOCK PER NODE (20000 blocks). R9 lesson: grid-striding this kernel at
// 2048 blocks cut TLP 10x on a latency-bound access pattern -> 230us (5x
// regression). Max block count is the proven-fast shape; do not fuse stats in.
__global__ __launch_bounds__(128) void gather_k(
    const unsigned short* __restrict__ XW, const int* __restrict__ offsets,
    const int* __restrict__ s_s, const float* __restrict__ w_s,
    unsigned short* __restrict__ H) {
  const int n = blockIdx.x;
  const int t = threadIdx.x;
  const int beg = offsets[n], end = offsets[n + 1];
  float4 acc = make_float4(0.f, 0.f, 0.f, 0.f);
  int i = beg;
  for (; i + 3 < end; i += 4) {
    const int   s0 = s_s[i],     s1 = s_s[i + 1];
    const int   s2 = s_s[i + 2], s3 = s_s[i + 3];
    const float w0 = w_s[i],     w1 = w_s[i + 1];
    const float w2 = w_s[i + 2], w3 = w_s[i + 3];
    const ushort4 v0 = *(const ushort4*)&XW[(size_t)s0 * HID + t * 4];
    const ushort4 v1 = *(const ushort4*)&XW[(size_t)s1 * HID + t * 4];
    const ushort4 v2 = *(const ushort4*)&XW[(size_t)s2 * HID + t * 4];
    const ushort4 v3 = *(const ushort4*)&XW[(size_t)s3 * HID + t * 4];
    acc.x = fmaf(w0, b2f(v0.x), acc.x); acc.y = fmaf(w0, b2f(v0.y), acc.y);
    acc.z = fmaf(w0, b2f(v0.z), acc.z); acc.w = fmaf(w0, b2f(v0.w), acc.w);
    acc.x = fmaf(w1, b2f(v1.x), acc.x); acc.y = fmaf(w1, b2f(v1.y), acc.y);
    acc.z = fmaf(w1, b2f(v1.z), acc.z); acc.w = fmaf(w1, b2f(v1.w), acc.w);
    acc.x = fmaf(w2, b2f(v2.x), acc.x); acc.y = fmaf(w2, b2f(v2.y), acc.y);
    acc.z = fmaf(w2, b2f(v2.z), acc.z); acc.w = fmaf(w2, b2f(v2.w), acc.w);
    acc.x = fmaf(w3, b2f(v3.x), acc.x); acc.y = fmaf(w3, b2f(v3.y), acc.y);
    acc.z = fmaf(w3, b2f(v3.z), acc.z); acc.w = fmaf(w3, b2f(v3.w), acc.w);
  }
  for (; i < end; i++) {
    const int   s = s_s[i];
    const float w = w_s[i];
    const ushort4 v = *(const ushort4*)&XW[(size_t)s * HID + t * 4];
    acc.x = fmaf(w, b2f(v.x), acc.x);
    acc.y = fmaf(w, b2f(v.y), acc.y);
    acc.z = fmaf(w, b2f(v.z), acc.z);
    acc.w = fmaf(w, b2f(v.w), acc.w);
  }
  ushort4 o; o.x = f2b(acc.x); o.y = f2b(acc.y); o.z = f2b(acc.z); o.w = f2b(acc.w);
  *(ushort4*)&H[(size_t)n * HID + t * 4] = o;
}

// ---------------- BN stats over bf16 H ----------------
__global__ __launch_bounds__(256) void bn_stats_k(
    const unsigned short* __restrict__ H, float* __restrict__ stats, int N)
{
  const int tx = threadIdx.x & 63;
  const int ty = threadIdx.x >> 6;
  const int col = blockIdx.x * 64 + tx;
  float s1 = 0.f, s2 = 0.f;
  for (int r = blockIdx.y * 4 + ty; r < N; r += gridDim.y * 4) {
    float v = b2f(H[(size_t)r * HID + col]);
    s1 += v; s2 += v * v;
  }
  __shared__ float red[2][4][64];
  red[0][ty][tx] = s1;
  red[1][ty][tx] = s2;
  __syncthreads();
  if (ty == 0) {
    s1 = red[0][0][tx] + red[0][1][tx] + red[0][2][tx] + red[0][3][tx];
    s2 = red[1][0][tx] + red[1][1][tx] + red[1][2][tx] + red[1][3][tx];
    atomicAdd(&stats[col], s1);
    atomicAdd(&stats[HID + col], s2);
  }
}

// ---------------- BN apply + ReLU: bf16 H -> bf16 h ----------------
__global__ __launch_bounds__(256) void bn_apply_k(
    const unsigned short* __restrict__ H, const float* __restrict__ stats,
    const float* __restrict__ gamma, const float* __restrict__ beta,
    unsigned short* __restrict__ out, int N)
{
  size_t gid = (size_t)blockIdx.x * 256 + threadIdx.x;
  size_t idx = gid * 4;
  if (idx >= (size_t)N * HID) return;
  int col = (int)(idx & (HID - 1));
  const ushort4 v = *(const ushort4*)&H[idx];
  float r[4] = {b2f(v.x), b2f(v.y), b2f(v.z), b2f(v.w)};
  ushort4 o;
  unsigned short* op = &o.x;
  #pragma unroll
  for (int i = 0; i < 4; i++) {
    int c = col + i;
    float mean = stats[c] * (1.0f / N);
    float var  = stats[HID + c] * (1.0f / N) - mean * mean;
    float scale = gamma[c] / sqrtf(var + BN_EPS);
    float shift = beta[c] - mean * scale;
    op[i] = f2b(fmaxf(fmaf(r[i], scale, shift), 0.0f));
  }
  *(ushort4*)&out[idx] = o;
}

// ---------------- bf16 MFMA GEMM, BK=64, swizzled LDS + XCD mapping ----
// C(f32) or C16(bf16) [M,NC] (+)= A[M,K] * Bt[NC,K]^T (+bias)
// R6/R8-proven depth-1 double-buffer. Tile + scheduling ledger (CLOSED):
//   BK=32 4-deep + sched_barrier pins: 95->117us (R2)
//   counted vmcnt(6) 3-buffer 72KB: FETCH 113->227MB, slower (R7)
//   gate-interleaved fused-cell1: +25% structurally (R4/R5)
//   BN=256 wide tile (R13): FETCH 360->274MB but occupancy 30->20%,
//     163.6->171.5us -- occupancy at 3 blk/CU beats halved A re-reads.
// BN=128/BM=64 (3 blk/CU) is the measured optimum for the wide gates GEMM.
// ntc=1: non-temporal stores for write-once/read-once outputs (R8/R11).
// Swizzle: row r's chunk c at slot (c+r)&7 -> 2-way bank aliasing (free).
template<int BM, int BN>
__global__ __launch_bounds__(256) void gemm_bf16_k(
    const unsigned short* __restrict__ A, int lda,
    const unsigned short* __restrict__ A2, int lda2, int ksplit,
    const unsigned short* __restrict__ Bt,
    float* __restrict__ C, unsigned short* __restrict__ C16,
    const float* __restrict__ bias,
    int M, int K, int Ksmall, int NC, int ldc, int acc, int ntc,
    int nrowb, int ncolb)
{
  const int b   = blockIdx.x;
  const int xcd = b & 7;
  const int j   = b >> 3;
  const int col_b = j % ncolb;
  const int row_b = (j / ncolb) * 8 + xcd;
  if (row_b >= nrowb) return;

  constexpr int MI  = 2;
  constexpr int ASZ = BM * 64;
  constexpr int BSZ = BN * 64;
  __shared__ unsigned short As[2 * ASZ];
  __shared__ unsigned short Bs[2 * BSZ];
  const int row0 = row_b * BM;
  const int col0 = col_b * BN;
  const int Kthis = (col0 < 1024) ? K : Ksmall;
  const int t    = threadIdx.x;
  const int lane = t & 63;
  const int w    = t >> 6;
  const int wro  = (BN == 128) ? (w >> 1) * 32 : w * 32;
  const int wco  = (BN == 128) ? (w & 1) * 64 : 0;
  const int q    = lane >> 4;
  const int l16  = lane & 15;

  f32x4 accr[MI][4] = {};

  auto stage = [&](int buf, int k0) {
    unsigned short* Ad = As + buf * ASZ;
    unsigned short* Bd = Bs + buf * BSZ;
    #pragma unroll
    for (int i = 0; i < BM / 32; i++) {
      int s  = t + i * 256;
      int r  = s >> 3, cq = s & 7;
      int kq = (cq - r) & 7;
      int gr = row0 + r; if (gr > M - 1) gr = M - 1;
      int kk = k0 + kq * 8;
      const unsigned short* bp = (kk < ksplit) ? A : A2;
      size_t off = (kk < ksplit) ? ((size_t)gr * lda + kk)
                                 : ((size_t)gr * lda2 + (kk - ksplit));
      gld_lds16(bp + off, Ad + (size_t)s * 8);
    }
    #pragma unroll
    for (int i = 0; i < BN / 32; i++) {
      int s  = t + i * 256;
      int r  = s >> 3, cq = s & 7;
      int kq = (cq - r) & 7;
      gld_lds16(Bt + (size_t)(col0 + r) * K + k0 + kq * 8, Bd + (size_t)s * 8);
    }
  };

  stage(0, 0);
  int cur = 0;
  for (int k0 = 0; k0 < Kthis; k0 += 64) {
    __syncthreads();
    if (k0 + 64 < Kthis) stage(cur ^ 1, k0 + 64);

    const unsigned short* Ac = As + cur * ASZ;
    const unsigned short* Bc = Bs + cur * BSZ;
    #pragma unroll
    for (int ks = 0; ks < 2; ks++) {
      bf16x8 af[MI], bfr[4];
      #pragma unroll
      for (int mi = 0; mi < MI; mi++) {
        int r = wro + mi * 16 + l16;
        int slot = (ks * 4 + q + r) & 7;
        af[mi] = *(const bf16x8*)&Ac[r * 64 + slot * 8];
      }
      #pragma unroll
      for (int ni = 0; ni < 4; ni++) {
        int r = wco + ni * 16 + l16;
        int slot = (ks * 4 + q + r) & 7;
        bfr[ni] = *(const bf16x8*)&Bc[r * 64 + slot * 8];
      }
      #pragma unroll
      for (int mi = 0; mi < MI; mi++)
        #pragma unroll
        for (int ni = 0; ni < 4; ni++)
          accr[mi][ni] = __builtin_amdgcn_mfma_f32_16x16x32_bf16(
              af[mi], bfr[ni], accr[mi][ni], 0, 0, 0);
    }
    cur ^= 1;
  }

  #pragma unroll
  for (int mi = 0; mi < MI; mi++) {
    #pragma unroll
    for (int ni = 0; ni < 4; ni++) {
      int col = col0 + wco + ni * 16 + l16;
      #pragma unroll
      for (int r = 0; r < 4; r++) {
        int row = row0 + wro + mi * 16 + q * 4 + r;
        if (row < M) {
          float v = accr[mi][ni][r];
          if (C16) {
            unsigned short hv = f2b(v);
            unsigned short* hp = &C16[(size_t)row * ldc + col];
            if (ntc) __builtin_nontemporal_store(hv, hp);
            else     *hp = hv;
          } else {
            float* cp = &C[(size_t)row * ldc + col];
            if (acc)       *cp += v;
            else if (bias) *cp  = v + bias[col];
            else if (ntc)  __builtin_nontemporal_store(v, cp);
            else           *cp  = v;
          }
        }
      }
    }
  }
}

// ---------------- LSTM cell part 1 (gate order f|g|i|o; bias added here) --------
// R11/R12: gates bf16; c state kept ONLY as bf16 in a16[:,512:] (fp32 cbuf
// eliminated -- frees bufH for a16 so CH doubles). cin16 = prev c (bf16).
__global__ __launch_bounds__(256) void cell1_k(
    const unsigned short* __restrict__ gates, const float* __restrict__ lb,
    const unsigned short* __restrict__ cin16, int ldc16,
    unsigned short* __restrict__ cout16, int ld16,
    int rows, int hasC)
{
  size_t gid = (size_t)blockIdx.x * 256 + threadIdx.x;
  if (gid >= (size_t)rows * HID) return;
  size_t row = gid >> 9;
  int    col = (int)(gid & (HID - 1));
  const unsigned short* g = &gates[row * G4];
  float ig = sigmoidf_(b2f(__builtin_nontemporal_load(&g[I_OFF + col])) + lb[col]);
  float gg = tanhf(b2f(__builtin_nontemporal_load(&g[G_OFF + col])) + lb[2 * HID + col]);
  float c;
  if (hasC) {
    float fg = sigmoidf_(b2f(__builtin_nontemporal_load(&g[F_OFF + col])) + lb[HID + col]);
    c = fg * b2f(cin16[row * ldc16 + col]) + ig * gg;
  } else {
    c = ig * gg;
  }
  cout16[row * ld16 + col] = f2b(c);
}

// ---------------- LSTM cell part 2: hy16 = sigma(gates_O + obuf + b_o)*tanh(c) ---
__global__ __launch_bounds__(256) void cell2_k(
    const unsigned short* __restrict__ gates, const unsigned short* __restrict__ obuf16,
    const float* __restrict__ lb, const unsigned short* __restrict__ cy16, int ldcy,
    unsigned short* __restrict__ hy16, int ld16, int rows)
{
  size_t gid = (size_t)blockIdx.x * 256 + threadIdx.x;
  if (gid >= (size_t)rows * HID) return;
  size_t row = gid >> 9;
  int    col = (int)(gid & (HID - 1));
  float ov = b2f(__builtin_nontemporal_load(&gates[row * G4 + O_OFF + col]));
  float og = sigmoidf_(ov + b2f(obuf16[row * HID + col]) + lb[3 * HID + col]);
  float h = og * tanhf(b2f(cy16[row * ldcy + col]));
  hy16[row * ld16 + col] = f2b(h);
}

// ---------------- fused final cell2 + output projection ----------------
__global__ __launch_bounds__(256) void cellout_k(
    const unsigned short* __restrict__ gates, const unsigned short* __restrict__ obuf16,
    const float* __restrict__ lb, const unsigned short* __restrict__ cy16, int ldcy,
    const float* __restrict__ W, const float* __restrict__ b,
    float* __restrict__ out, int rows)
{
  int wave = (int)(((size_t)blockIdx.x * 256 + threadIdx.x) >> 6);
  int lane = threadIdx.x & 63;
  if (wave >= rows) return;
  const unsigned short* g  = &gates[(size_t)wave * G4 + O_OFF];
  const unsigned short* ob = &obuf16[(size_t)wave * HID];
  const unsigned short* cr = &cy16[(size_t)wave * ldcy];
  float hy[8];
  #pragma unroll
  for (int j = 0; j < 8; j++) {
    int k = lane + j * 64;
    float og = sigmoidf_(b2f(__builtin_nontemporal_load(&g[k])) + b2f(ob[k]) + lb[3 * HID + k]);
    hy[j] = og * tanhf(b2f(cr[k]));
  }
  float acc[12] = {};
  #pragma unroll
  for (int j = 0; j < 8; j++) {
    int k = lane + j * 64;
    const float* wr = &W[k * 12];
    #pragma unroll
    for (int p = 0; p < 12; p++) acc[p] = fmaf(hy[j], wr[p], acc[p]);
  }
  #pragma unroll
  for (int p = 0; p < 12; p++) {
    float v = acc[p];
    #pragma unroll
    for (int off = 32; off > 0; off >>= 1) v += __shfl_down(v, off);
    if (lane == 0) out[(size_t)wave * 12 + p] = v + b[p];
  }
}

extern "C" void kernel_launch(void* const* d_in, const int* in_sizes, int n_in,
                              void* d_out, int out_size, void* d_ws, size_t ws_size,
                              hipStream_t stream) {
  const float* x     = (const float*)d_in[0];
  const int*   ei    = (const int*)d_in[1];
  const float* ew    = (const float*)d_in[2];
  const float* gcn0W = (const float*)d_in[3];
  const float* gcnW  = (const float*)d_in[5];
  const float* gamma = (const float*)d_in[7];
  const float* beta  = (const float*)d_in[8];
  const float* wih   = (const float*)d_in[9];
  const float* whh   = (const float*)d_in[10];
  const float* wch   = (const float*)d_in[11];
  const float* lstmb = (const float*)d_in[12];
  const float* outW  = (const float*)d_in[13];
  const float* outb  = (const float*)d_in[14];
  float* out = (float*)d_out;

  const int* src = ei;
  const int* dst = ei + N_EDGES;

  // R12: gates are bf16 -> half the bytes per row -> CH doubles within the
  // SAME workspace region the fp32 layout used (byte-exact fit).
  const int CHL = (ws_size >= (size_t)215000000) ? 10000 : 5000;  // layout unit
  const int CH  = 2 * CHL;
  const int NCHUNK = N_NODES / CH;

  // -------- workspace layout (byte offsets identical to R11) --------
  const size_t NH = (size_t)N_NODES * HID;
  float* ws = (float*)d_ws;
  float* gates = ws;                                 // CHL*2048 fp32 bytes = CH*2048 bf16
  float* bufH  = gates + (size_t)CHL * G4;           // NH fp32 (GCN H / LSTM a16)
  unsigned short* hbA16 = (unsigned short*)(bufH + NH);
  unsigned short* hbB16 = hbA16 + NH;                // GCN scratch / LSTM obuf16
  unsigned short* x16   = hbB16 + NH;                // scratch (scan block sums)
  unsigned short* g0t   = x16 + (size_t)N_NODES * IN_CH;
  unsigned short* g1t   = g0t   + 512 * 64;
  unsigned short* g2t   = g1t   + 512 * 512;
  unsigned short* wih0t = g2t   + 512 * 512;             // [1536,512] rows g|i|o
  unsigned short* wcat3 = wih0t + (size_t)1536 * 512;    // [2048,1536] fused L1 B
  unsigned short* wch0ot= wcat3 + (size_t)2048 * 1536;   // [512,512]
  unsigned short* wch1ot= wch0ot + 512 * 512;            // [512,512]
  unsigned short* wend  = wch1ot + 512 * 512;
  float* stats = (float*)wend;                       // 3 layers x 1024 floats
  int*   csr   = (int*)(stats + 3072);
  int*   counts  = csr;
  int*   offsets = csr + 20032;
  int*   cpos    = csr + 40064;
  int*   s_s     = csr + 60096;
  float* w_s     = (float*)(csr + 380096);
  int*   bsum    = (int*)x16;                        // 157 ints, prologue-only

  unsigned short* bufH16 = (unsigned short*)bufH;  // bf16 H during GCN
  // LSTM-phase buffers (GCN scratch reused; no temporal overlap):
  unsigned short* gates16 = (unsigned short*)gates;  // bf16 [CH, G4]
  unsigned short* a16     = (unsigned short*)bufH;   // bf16 [CH,1024] = [hy | c]
  unsigned short* obuf16  = hbB16;                   // bf16 [CH,512] o-peephole

  const dim3 blk(256);
  auto gemm128 = [&](const unsigned short* A, int lda,
                     const unsigned short* A2, int lda2, int ksplit,
                     const unsigned short* Bt, unsigned short* C16,
                     int M, int K, int Ksmall, int NC, int ldc) {
    int nrowb = (M + 63) / 64;
    int ncolb = NC / 128;
    int nblocks = 8 * ((nrowb + 7) / 8) * ncolb;
    hipLaunchKernelGGL((gemm_bf16_k<64, 128>), dim3(nblocks), blk, 0, stream,
                       A, lda, A2, lda2, ksplit, Bt, (float*)nullptr, C16,
                       (const float*)nullptr,
                       M, K, Ksmall, NC, ldc, 0, /*ntc=*/1, nrowb, ncolb);
  };
  auto gemm64 = [&](const unsigned short* A, int lda,
                    const unsigned short* Bt, float* C, unsigned short* C16,
                    const float* bias, int M, int K, int NC, int ldc, int acc,
                    int ntc) {
    int nrowb = (M + 127) / 128;
    int ncolb = NC / 64;
    int nblocks = 8 * ((nrowb + 7) / 8) * ncolb;
    hipLaunchKernelGGL((gemm_bf16_k<128, 64>), dim3(nblocks), blk, 0, stream,
                       A, lda, A, lda, K, Bt, C, C16, bias,
                       M, K, K, NC, ldc, acc, ntc, nrowb, ncolb);
  };
  auto zero = [&](float* p, size_t n) {
    hipLaunchKernelGGL(zero_k, dim3((unsigned)((n / 4 + 255) / 256)), blk, 0, stream, p, n);
  };

  // -------- weight prep: all 18 transposes in ONE launch --------
  const float* wih1 = wih + (size_t)HID * G4;
  const float* whh1 = whh + (size_t)HID * G4;
  const float* wch1 = wch + (size_t)HID * 3 * HID;
  {
    TcvtBatch tb;
    int n = 0;
    auto add = [&](const float* W, unsigned short* Wt, int K, int NC, int ldw, int ldo) {
      tb.d[n++] = TcvtDesc{W, Wt, K, NC, ldw, ldo};
    };
    add(gcn0W, g0t, IN_CH, HID, HID, IN_CH);
    add(gcnW,                     g1t, HID, HID, HID, HID);
    add(gcnW + (size_t)HID * HID, g2t, HID, HID, HID, HID);
    // layer-0 Wih rows [g|i|o] (f dead: c=0)
    add(wih + 2 * HID, wih0t,                      HID, HID, G4, HID);  // g
    add(wih,           wih0t + (size_t)512 * 512,  HID, HID, G4, HID);  // i
    add(wih + 3 * HID, wih0t + (size_t)1024 * 512, HID, HID, G4, HID);  // o
    // fused layer-1 B [2048 x 1536]: rows f,g K=1536 (ih|hh|peep); i,o K=1024
    add(wih1 + HID,     wcat3 + (size_t)F_OFF * 1536,        HID, HID, G4, 1536);
    add(whh1 + HID,     wcat3 + (size_t)F_OFF * 1536 + 512,  HID, HID, G4, 1536);
    add(wch1 + HID,     wcat3 + (size_t)F_OFF * 1536 + 1024, HID, HID, 3 * HID, 1536);
    add(wih1 + 2 * HID, wcat3 + (size_t)G_OFF * 1536,        HID, HID, G4, 1536);
    add(whh1 + 2 * HID, wcat3 + (size_t)G_OFF * 1536 + 512,  HID, HID, G4, 1536);
    add(wch1,           wcat3 + (size_t)G_OFF * 1536 + 1024, HID, HID, 3 * HID, 1536);
    add(wih1,           wcat3 + (size_t)I_OFF * 1536,        HID, HID, G4, 1536);
    add(whh1,           wcat3 + (size_t)I_OFF * 1536 + 512,  HID, HID, G4, 1536);
    add(wih1 + 3 * HID, wcat3 + (size_t)O_OFF * 1536,        HID, HID, G4, 1536);
    add(whh1 + 3 * HID, wcat3 + (size_t)O_OFF * 1536 + 512,  HID, HID, G4, 1536);
    add(wch + 2 * HID,  wch0ot, HID, HID, 3 * HID, HID);   // Wch0 o-peephole
    add(wch1 + 2 * HID, wch1ot, HID, HID, 3 * HID, HID);   // Wch1 o-peephole
    hipLaunchKernelGGL(tcvtb_k, dim3(16, 16, 18), dim3(32, 8), 0, stream, tb);
  }

  // -------- CSR build; stats+counts zeroed in ONE launch (contiguous) --------
  const int e_blocks = (N_EDGES + 255) / 256;
  const int nscanb = (N_NODES + 127) / 128;   // 157
  zero(stats, 3 * 1024 + N_NODES);            // covers stats AND counts
  hipLaunchKernelGGL(hist_k, dim3(e_blocks), blk, 0, stream, dst, counts);
  hipLaunchKernelGGL(scan1_k, dim3(nscanb), dim3(128), 0, stream,
                     counts, offsets, bsum, N_NODES);
  hipLaunchKernelGGL(scan2_k, dim3(nscanb), dim3(128), 0, stream,
                     bsum, offsets, cpos, N_NODES, nscanb);
  hipLaunchKernelGGL(fill_k, dim3(e_blocks), blk, 0, stream, src, dst, ew, cpos, s_s, w_s);

  // -------- GCN layer 0: gather-first (linearity), direct f32 input --------
  hipLaunchKernelGGL(gather64_k, dim3(N_NODES / 4), dim3(64), 0, stream,
                     x, offsets, s_s, w_s, hbB16);
  gemm64(hbB16, IN_CH, g0t, nullptr, bufH16, nullptr, N_NODES, IN_CH, HID, HID, 0, 0);
  hipLaunchKernelGGL(bn_stats_k, dim3(8, 64), blk, 0, stream, bufH16, stats, N_NODES);
  hipLaunchKernelGGL(bn_apply_k, dim3((unsigned)(NH / 4 / 256)), blk, 0, stream,
                     bufH16, stats, gamma, beta, hbA16, N_NODES);

  // -------- GCN layers 1,2: GEMM -> gather -> BN stats -> BN apply --------
  // (XW outputs NOT nt: gather re-reads each row ~16x, wants them cached.)
  const unsigned short* gWt2[2] = {g1t, g2t};
  const unsigned short* gA2[2]  = {hbA16, hbB16};
  unsigned short*       gXW2[2] = {hbB16, hbA16};
  unsigned short*       gO2[2]  = {hbB16, hbA16};
  for (int l = 0; l < 2; l++) {
    gemm64(gA2[l], HID, gWt2[l], nullptr, gXW2[l], nullptr, N_NODES, HID, HID, HID, 0, 0);
    hipLaunchKernelGGL(gather_k, dim3(N_NODES), dim3(128), 0, stream,
                       gXW2[l], offsets, s_s, w_s, bufH16);
    hipLaunchKernelGGL(bn_stats_k, dim3(8, 64), blk, 0, stream, bufH16,
                       stats + (l + 1) * 1024, N_NODES);
    hipLaunchKernelGGL(bn_apply_k, dim3((unsigned)(NH / 4 / 256)), blk, 0, stream,
                       bufH16, stats + (l + 1) * 1024, gamma + (l + 1) * HID,
                       beta + (l + 1) * HID, gO2[l], N_NODES);
  }
  unsigned short* hfin16 = hbA16;
  // After GCN: hbB16 (layer-1 h) and bufH (pre-BN H) are dead -> reuse as
  // obuf16 and a16 for the LSTM phase. hfin16=hbA16 preserved.

  // -------- LSTM + output, chunked (CH doubled vs R11; often NCHUNK=1) ------
  for (int ci = 0; ci < NCHUNK; ci++) {
    const int r0 = ci * CH;
    const unsigned short* h_c = hfin16 + (size_t)r0 * HID;
    const int cell_blocks = (int)(((size_t)CH * HID + 255) / 256);

    // layer 0 (h=c=0, f dead): gates16[G|I|O] = bf16(h @ Wih0_gio), nt stores
    gemm128(h_c, HID, h_c, HID, HID, wih0t, gates16 + G_OFF,
            CH, HID, HID, 1536, G4);
    // c0 -> a16[:,512:] bf16
    hipLaunchKernelGGL(cell1_k, dim3(cell_blocks), blk, 0, stream,
                       gates16, lstmb, (const unsigned short*)nullptr, 0,
                       a16 + 512, 1024, CH, 0);
    // o peephole L0: obuf16 = bf16(c0 @ Wch0_o), nt (read-once by cell2)
    gemm64(a16 + 512, 1024, wch0ot, nullptr, obuf16, nullptr, CH, HID, HID, HID, 0, 1);
    // hy0 -> a16[:,0:512] bf16
    hipLaunchKernelGGL(cell2_k, dim3(cell_blocks), blk, 0, stream,
                       gates16, obuf16, lstmb, a16 + 512, 1024, a16, 1024, CH);

    // layer 1 fused: gates16 = bf16([h | hy0 | c0] @ wcat3) (split-A;
    // f,g K=1536, i,o K=1024), nt stores
    gemm128(h_c, HID, a16, 1024, HID, wcat3, gates16,
            CH, 1536, 1024, G4, G4);
    // c1 -> a16[:,512:] (reads c0 from same slot elementwise-before-write)
    hipLaunchKernelGGL(cell1_k, dim3(cell_blocks), blk, 0, stream,
                       gates16, lstmb + G4, a16 + 512, 1024,
                       a16 + 512, 1024, CH, 1);
    // o peephole L1: obuf16 = bf16(c1 @ Wch1_o), nt (read-once by cellout)
    gemm64(a16 + 512, 1024, wch1ot, nullptr, obuf16, nullptr, CH, HID, HID, HID, 0, 1);
    // fused cell2 + output projection
    hipLaunchKernelGGL(cellout_k, dim3((CH * 64 + 255) / 256), blk, 0, stream,
                       gates16, obuf16, lstmb + G4, a16 + 512, 1024, outW, outb,
                       out + (size_t)r0 * 12, CH);
  }
}

// Round 15
// 747.171 us; speedup vs baseline: 1.0305x; 1.0054x over previous
//
#include <hip/hip_runtime.h>
#include <cstddef>

#define N_NODES 20000
#define N_EDGES 320000
#define IN_CH   64
#define HID     512
#define G4      2048
#define BN_EPS  1e-5f
// gate order in gates buffer: [f | g | i | o]
#define F_OFF   0
#define G_OFF   512
#define I_OFF   1024
#define O_OFF   1536

typedef __attribute__((ext_vector_type(8))) __bf16 bf16x8;
typedef __attribute__((ext_vector_type(4))) float f32x4;

__device__ __forceinline__ float sigmoidf_(float x) {
  return 1.0f / (1.0f + expf(-x));
}

// fp32 -> bf16 (RNE)
__device__ __forceinline__ unsigned short f2b(float f) {
  unsigned int u = __float_as_uint(f);
  u += 0x7FFFu + ((u >> 16) & 1u);
  return (unsigned short)(u >> 16);
}
__device__ __forceinline__ float b2f(unsigned short u) {
  return __uint_as_float(((unsigned int)u) << 16);
}

__device__ __forceinline__ void gld_lds16(const unsigned short* g, unsigned short* l) {
  __builtin_amdgcn_global_load_lds(
      (const __attribute__((address_space(1))) unsigned int*)(const void*)g,
      (__attribute__((address_space(3))) unsigned int*)(void*)l, 16, 0, 0);
}

// ---------------- zero fill ----------------
__global__ __launch_bounds__(256) void zero_k(float* __restrict__ p, size_t n) {
  size_t i = ((size_t)blockIdx.x * 256 + threadIdx.x) * 4;
  if (i + 3 < n) {
    *(float4*)&p[i] = make_float4(0.f, 0.f, 0.f, 0.f);
  } else {
    for (; i < n; i++) p[i] = 0.f;
  }
}

// ---------------- batched transpose + cvt: 18 weight panels in ONE launch ----
// Wt[n*ldo + k] = bf16(W[k*ldw + n]); blockIdx.z selects descriptor.
// (R4/R5 lesson: gate-interleaved B + fused cell1 epilogue measured SLOWER --
// split-gate layout with variable-K early exit is the proven structure.)
struct TcvtDesc { const float* W; unsigned short* Wt; int K, NC, ldw, ldo; };
struct TcvtBatch { TcvtDesc d[18]; };

__global__ void tcvtb_k(TcvtBatch batch) {
  const TcvtDesc dd = batch.d[blockIdx.z];
  __shared__ float tile[32][33];
  const int n0 = blockIdx.x * 32, k0 = blockIdx.y * 32;
  if (n0 >= dd.NC || k0 >= dd.K) return;   // uniform per-block exit
  const int tx = threadIdx.x, ty = threadIdx.y;  // 32 x 8
  #pragma unroll
  for (int i = 0; i < 32; i += 8) {
    int k = k0 + ty + i, n = n0 + tx;
    tile[ty + i][tx] = (k < dd.K && n < dd.NC) ? dd.W[(size_t)k * dd.ldw + n] : 0.f;
  }
  __syncthreads();
  #pragma unroll
  for (int i = 0; i < 32; i += 8) {
    int n = n0 + ty + i, k = k0 + tx;
    if (n < dd.NC && k < dd.K) dd.Wt[(size_t)n * dd.ldo + k] = f2b(tile[tx][ty + i]);
  }
}

// ---------------- CSR build ----------------
__global__ __launch_bounds__(256) void hist_k(const int* __restrict__ dst,
                                              int* __restrict__ counts) {
  int e = blockIdx.x * 256 + threadIdx.x;
  if (e < N_EDGES) atomicAdd(&counts[dst[e]], 1);
}

// Hierarchical exclusive scan (R10: replaces single-block scan's ~440 serial
// barriers on one CU; worth ~47us end-to-end).
__global__ __launch_bounds__(128) void scan1_k(const int* __restrict__ counts,
                                               int* __restrict__ offsets,
                                               int* __restrict__ bsum, int n) {
  __shared__ int sh[128];
  const int b = blockIdx.x, t = threadIdx.x;
  const int i = b * 128 + t;
  const int v = (i < n) ? counts[i] : 0;
  sh[t] = v;
  __syncthreads();
  #pragma unroll
  for (int off = 1; off < 128; off <<= 1) {
    int u = (t >= off) ? sh[t - off] : 0;
    __syncthreads();
    sh[t] += u;
    __syncthreads();
  }
  if (i < n) offsets[i] = sh[t] - v;   // exclusive within block (no base yet)
  if (t == 127) bsum[b] = sh[127];
}

__global__ __launch_bounds__(128) void scan2_k(const int* __restrict__ bsum,
                                               int* __restrict__ offsets,
                                               int* __restrict__ pos,
                                               int n, int nb) {
  __shared__ int red[128];
  __shared__ int base_s;
  const int b = blockIdx.x, t = threadIdx.x;
  int part = 0;
  if (t < b) part += bsum[t];
  if (t + 128 < b) part += bsum[t + 128];
  red[t] = part;
  __syncthreads();
  if (t < 64) {
    int v = red[t] + red[t + 64];
    #pragma unroll
    for (int off = 32; off > 0; off >>= 1) v += __shfl_down(v, off);
    if (t == 0) base_s = v;
  }
  __syncthreads();
  const int i = b * 128 + t;
  if (i < n) {
    int off = base_s + offsets[i];
    offsets[i] = off;
    pos[i] = off;
  }
  if (b == nb - 1 && t == 0) offsets[n] = base_s + bsum[b];
}

__global__ __launch_bounds__(256) void fill_k(
    const int* __restrict__ src, const int* __restrict__ dst,
    const float* __restrict__ ew, int* __restrict__ pos,
    int* __restrict__ s_s, float* __restrict__ w_s) {
  int e = blockIdx.x * 256 + threadIdx.x;
  if (e >= N_EDGES) return;
  int p = atomicAdd(&pos[dst[e]], 1);
  s_s[p] = src[e];
  w_s[p] = ew[e];
}

// ---------------- L0 gather directly on f32 input: xg = bf16(S·x) ------------
// Reads x f32 (5MB, L3-resident). 4-way unrolled edge loop: 4 independent
// row loads in flight per iteration (latency-bound otherwise).
__global__ __launch_bounds__(64) void gather64_k(
    const float* __restrict__ x, const int* __restrict__ offsets,
    const int* __restrict__ s_s, const float* __restrict__ w_s,
    unsigned short* __restrict__ xg) {
  const int sub = threadIdx.x >> 4;
  const int cg  = threadIdx.x & 15;
  const int n   = blockIdx.x * 4 + sub;
  const int beg = offsets[n], end = offsets[n + 1];
  float4 acc = make_float4(0.f, 0.f, 0.f, 0.f);
  int i = beg;
  for (; i + 3 < end; i += 4) {
    const int   s0 = s_s[i],     s1 = s_s[i + 1];
    const int   s2 = s_s[i + 2], s3 = s_s[i + 3];
    const float w0 = w_s[i],     w1 = w_s[i + 1];
    const float w2 = w_s[i + 2], w3 = w_s[i + 3];
    const float4 v0 = *(const float4*)&x[(size_t)s0 * IN_CH + cg * 4];
    const float4 v1 = *(const float4*)&x[(size_t)s1 * IN_CH + cg * 4];
    const float4 v2 = *(const float4*)&x[(size_t)s2 * IN_CH + cg * 4];
    const float4 v3 = *(const float4*)&x[(size_t)s3 * IN_CH + cg * 4];
    acc.x = fmaf(w0, v0.x, acc.x); acc.y = fmaf(w0, v0.y, acc.y);
    acc.z = fmaf(w0, v0.z, acc.z); acc.w = fmaf(w0, v0.w, acc.w);
    acc.x = fmaf(w1, v1.x, acc.x); acc.y = fmaf(w1, v1.y, acc.y);
    acc.z = fmaf(w1, v1.z, acc.z); acc.w = fmaf(w1, v1.w, acc.w);
    acc.x = fmaf(w2, v2.x, acc.x); acc.y = fmaf(w2, v2.y, acc.y);
    acc.z = fmaf(w2, v2.z, acc.z); acc.w = fmaf(w2, v2.w, acc.w);
    acc.x = fmaf(w3, v3.x, acc.x); acc.y = fmaf(w3, v3.y, acc.y);
    acc.z = fmaf(w3, v3.z, acc.z); acc.w = fmaf(w3, v3.w, acc.w);
  }
  for (; i < end; i++) {
    const int   s = s_s[i];
    const float w = w_s[i];
    const float4 v = *(const float4*)&x[(size_t)s * IN_CH + cg * 4];
    acc.x = fmaf(w, v.x, acc.x);
    acc.y = fmaf(w, v.y, acc.y);
    acc.z = fmaf(w, v.z, acc.z);
    acc.w = fmaf(w, v.w, acc.w);
  }
  ushort4 o; o.x = f2b(acc.x); o.y = f2b(acc.y); o.z = f2b(acc.z); o.w = f2b(acc.w);
  *(ushort4*)&xg[(size_t)n * IN_CH + cg * 4] = o;
}

// ---------------- aggregation gather (bf16 XW -> bf16 H), 4-way pipelined ------
// ONE BLOCK PER NODE (20000 blocks). R9 lesson: grid-striding this kernel at
// 2048 blocks cut TLP 10x on a latency-bound access pattern -> 230us (5x
// regression). Max block count is the proven-fast shape; do not fuse stats in.
__global__ __launch_bounds__(128) void gather_k(
    const unsigned short* __restrict__ XW, const int* __restrict__ offsets,
    const int* __restrict__ s_s, const float* __restrict__ w_s,
    unsigned short* __restrict__ H) {
  const int n = blockIdx.x;
  const int t = threadIdx.x;
  const int beg = offsets[n], end = offsets[n + 1];
  float4 acc = make_float4(0.f, 0.f, 0.f, 0.f);
  int i = beg;
  for (; i + 3 < end; i += 4) {
    const int   s0 = s_s[i],     s1 = s_s[i + 1];
    const int   s2 = s_s[i + 2], s3 = s_s[i + 3];
    const float w0 = w_s[i],     w1 = w_s[i + 1];
    const float w2 = w_s[i + 2], w3 = w_s[i + 3];
    const ushort4 v0 = *(const ushort4*)&XW[(size_t)s0 * HID + t * 4];
    const ushort4 v1 = *(const ushort4*)&XW[(size_t)s1 * HID + t * 4];
    const ushort4 v2 = *(const ushort4*)&XW[(size_t)s2 * HID + t * 4];
    const ushort4 v3 = *(const ushort4*)&XW[(size_t)s3 * HID + t * 4];
    acc.x = fmaf(w0, b2f(v0.x), acc.x); acc.y = fmaf(w0, b2f(v0.y), acc.y);
    acc.z = fmaf(w0, b2f(v0.z), acc.z); acc.w = fmaf(w0, b2f(v0.w), acc.w);
    acc.x = fmaf(w1, b2f(v1.x), acc.x); acc.y = fmaf(w1, b2f(v1.y), acc.y);
    acc.z = fmaf(w1, b2f(v1.z), acc.z); acc.w = fmaf(w1, b2f(v1.w), acc.w);
    acc.x = fmaf(w2, b2f(v2.x), acc.x); acc.y = fmaf(w2, b2f(v2.y), acc.y);
    acc.z = fmaf(w2, b2f(v2.z), acc.z); acc.w = fmaf(w2, b2f(v2.w), acc.w);
    acc.x = fmaf(w3, b2f(v3.x), acc.x); acc.y = fmaf(w3, b2f(v3.y), acc.y);
    acc.z = fmaf(w3, b2f(v3.z), acc.z); acc.w = fmaf(w3, b2f(v3.w), acc.w);
  }
  for (; i < end; i++) {
    const int   s = s_s[i];
    const float w = w_s[i];
    const ushort4 v = *(const ushort4*)&XW[(size_t)s * HID + t * 4];
    acc.x = fmaf(w, b2f(v.x), acc.x);
    acc.y = fmaf(w, b2f(v.y), acc.y);
    acc.z = fmaf(w, b2f(v.z), acc.z);
    acc.w = fmaf(w, b2f(v.w), acc.w);
  }
  ushort4 o; o.x = f2b(acc.x); o.y = f2b(acc.y); o.z = f2b(acc.z); o.w = f2b(acc.w);
  *(ushort4*)&H[(size_t)n * HID + t * 4] = o;
}

// ---------------- BN stats over bf16 H ----------------
__global__ __launch_bounds__(256) void bn_stats_k(
    const unsigned short* __restrict__ H, float* __restrict__ stats, int N)
{
  const int tx = threadIdx.x & 63;
  const int ty = threadIdx.x >> 6;
  const int col = blockIdx.x * 64 + tx;
  float s1 = 0.f, s2 = 0.f;
  for (int r = blockIdx.y * 4 + ty; r < N; r += gridDim.y * 4) {
    float v = b2f(H[(size_t)r * HID + col]);
    s1 += v; s2 += v * v;
  }
  __shared__ float red[2][4][64];
  red[0][ty][tx] = s1;
  red[1][ty][tx] = s2;
  __syncthreads();
  if (ty == 0) {
    s1 = red[0][0][tx] + red[0][1][tx] + red[0][2][tx] + red[0][3][tx];
    s2 = red[1][0][tx] + red[1][1][tx] + red[1][2][tx] + red[1][3][tx];
    atomicAdd(&stats[col], s1);
    atomicAdd(&stats[HID + col], s2);
  }
}

// ---------------- BN apply + ReLU: bf16 H -> bf16 h ----------------
__global__ __launch_bounds__(256) void bn_apply_k(
    const unsigned short* __restrict__ H, const float* __restrict__ stats,
    const float* __restrict__ gamma, const float* __restrict__ beta,
    unsigned short* __restrict__ out, int N)
{
  size_t gid = (size_t)blockIdx.x * 256 + threadIdx.x;
  size_t idx = gid * 4;
  if (idx >= (size_t)N * HID) return;
  int col = (int)(idx & (HID - 1));
  const ushort4 v = *(const ushort4*)&H[idx];
  float r[4] = {b2f(v.x), b2f(v.y), b2f(v.z), b2f(v.w)};
  ushort4 o;
  unsigned short* op = &o.x;
  #pragma unroll
  for (int i = 0; i < 4; i++) {
    int c = col + i;
    float mean = stats[c] * (1.0f / N);
    float var  = stats[HID + c] * (1.0f / N) - mean * mean;
    float scale = gamma[c] / sqrtf(var + BN_EPS);
    float shift = beta[c] - mean * scale;
    op[i] = f2b(fmaxf(fmaf(r[i], scale, shift), 0.0f));
  }
  *(ushort4*)&out[idx] = o;
}

// ---------------- bf16 MFMA GEMM, BK=64, swizzled LDS + XCD mapping ----
// C(f32) or C16(bf16) [M,NC] (+)= A[M,K] * Bt[NC,K]^T (+bias)
// R6/R8-proven depth-1 double-buffer. Tile + scheduling ledger (CLOSED):
//   BK=32 4-deep + sched_barrier pins: 95->117us (R2)
//   counted vmcnt(6) 3-buffer 72KB: FETCH 113->227MB, slower (R7)
//   gate-interleaved fused-cell1: +25% structurally (R4/R5)
//   BN=256 wide tile (R13): occupancy 30->20% beats halved A re-reads; slower.
// BM=64/BN=128 (3 blk/CU, ncolb minimal) is the measured optimum -- R15 also
// routes all NC=512 GEMMs through it (ncolb 8->4 halves A re-reads vs
// the old <128,64> path).
// ntc=1: non-temporal stores for write-once/read-once outputs (R8/R11).
// Swizzle: row r's chunk c at slot (c+r)&7 -> 2-way bank aliasing (free).
template<int BM, int BN>
__global__ __launch_bounds__(256) void gemm_bf16_k(
    const unsigned short* __restrict__ A, int lda,
    const unsigned short* __restrict__ A2, int lda2, int ksplit,
    const unsigned short* __restrict__ Bt,
    float* __restrict__ C, unsigned short* __restrict__ C16,
    const float* __restrict__ bias,
    int M, int K, int Ksmall, int NC, int ldc, int acc, int ntc,
    int nrowb, int ncolb)
{
  const int b   = blockIdx.x;
  const int xcd = b & 7;
  const int j   = b >> 3;
  const int col_b = j % ncolb;
  const int row_b = (j / ncolb) * 8 + xcd;
  if (row_b >= nrowb) return;

  constexpr int MI  = 2;
  constexpr int ASZ = BM * 64;
  constexpr int BSZ = BN * 64;
  __shared__ unsigned short As[2 * ASZ];
  __shared__ unsigned short Bs[2 * BSZ];
  const int row0 = row_b * BM;
  const int col0 = col_b * BN;
  const int Kthis = (col0 < 1024) ? K : Ksmall;
  const int t    = threadIdx.x;
  const int lane = t & 63;
  const int w    = t >> 6;
  const int wro  = (BN == 128) ? (w >> 1) * 32 : w * 32;
  const int wco  = (BN == 128) ? (w & 1) * 64 : 0;
  const int q    = lane >> 4;
  const int l16  = lane & 15;

  f32x4 accr[MI][4] = {};

  auto stage = [&](int buf, int k0) {
    unsigned short* Ad = As + buf * ASZ;
    unsigned short* Bd = Bs + buf * BSZ;
    #pragma unroll
    for (int i = 0; i < BM / 32; i++) {
      int s  = t + i * 256;
      int r  = s >> 3, cq = s & 7;
      int kq = (cq - r) & 7;
      int gr = row0 + r; if (gr > M - 1) gr = M - 1;
      int kk = k0 + kq * 8;
      const unsigned short* bp = (kk < ksplit) ? A : A2;
      size_t off = (kk < ksplit) ? ((size_t)gr * lda + kk)
                                 : ((size_t)gr * lda2 + (kk - ksplit));
      gld_lds16(bp + off, Ad + (size_t)s * 8);
    }
    #pragma unroll
    for (int i = 0; i < BN / 32; i++) {
      int s  = t + i * 256;
      int r  = s >> 3, cq = s & 7;
      int kq = (cq - r) & 7;
      gld_lds16(Bt + (size_t)(col0 + r) * K + k0 + kq * 8, Bd + (size_t)s * 8);
    }
  };

  stage(0, 0);
  int cur = 0;
  for (int k0 = 0; k0 < Kthis; k0 += 64) {
    __syncthreads();
    if (k0 + 64 < Kthis) stage(cur ^ 1, k0 + 64);

    const unsigned short* Ac = As + cur * ASZ;
    const unsigned short* Bc = Bs + cur * BSZ;
    #pragma unroll
    for (int ks = 0; ks < 2; ks++) {
      bf16x8 af[MI], bfr[4];
      #pragma unroll
      for (int mi = 0; mi < MI; mi++) {
        int r = wro + mi * 16 + l16;
        int slot = (ks * 4 + q + r) & 7;
        af[mi] = *(const bf16x8*)&Ac[r * 64 + slot * 8];
      }
      #pragma unroll
      for (int ni = 0; ni < 4; ni++) {
        int r = wco + ni * 16 + l16;
        int slot = (ks * 4 + q + r) & 7;
        bfr[ni] = *(const bf16x8*)&Bc[r * 64 + slot * 8];
      }
      #pragma unroll
      for (int mi = 0; mi < MI; mi++)
        #pragma unroll
        for (int ni = 0; ni < 4; ni++)
          accr[mi][ni] = __builtin_amdgcn_mfma_f32_16x16x32_bf16(
              af[mi], bfr[ni], accr[mi][ni], 0, 0, 0);
    }
    cur ^= 1;
  }

  #pragma unroll
  for (int mi = 0; mi < MI; mi++) {
    #pragma unroll
    for (int ni = 0; ni < 4; ni++) {
      int col = col0 + wco + ni * 16 + l16;
      #pragma unroll
      for (int r = 0; r < 4; r++) {
        int row = row0 + wro + mi * 16 + q * 4 + r;
        if (row < M) {
          float v = accr[mi][ni][r];
          if (C16) {
            unsigned short hv = f2b(v);
            unsigned short* hp = &C16[(size_t)row * ldc + col];
            if (ntc) __builtin_nontemporal_store(hv, hp);
            else     *hp = hv;
          } else {
            float* cp = &C[(size_t)row * ldc + col];
            if (acc)       *cp += v;
            else if (bias) *cp  = v + bias[col];
            else if (ntc)  __builtin_nontemporal_store(v, cp);
            else           *cp  = v;
          }
        }
      }
    }
  }
}

// ---------------- LSTM cell part 1 (gate order f|g|i|o; bias added here) --------
// R11/R12: gates bf16; c state kept ONLY as bf16 in a16[:,512:] (fp32 cbuf
// eliminated -- frees bufH for a16 so CH doubles). cin16 = prev c (bf16).
__global__ __launch_bounds__(256) void cell1_k(
    const unsigned short* __restrict__ gates, const float* __restrict__ lb,
    const unsigned short* __restrict__ cin16, int ldc16,
    unsigned short* __restrict__ cout16, int ld16,
    int rows, int hasC)
{
  size_t gid = (size_t)blockIdx.x * 256 + threadIdx.x;
  if (gid >= (size_t)rows * HID) return;
  size_t row = gid >> 9;
  int    col = (int)(gid & (HID - 1));
  const unsigned short* g = &gates[row * G4];
  float ig = sigmoidf_(b2f(__builtin_nontemporal_load(&g[I_OFF + col])) + lb[col]);
  float gg = tanhf(b2f(__builtin_nontemporal_load(&g[G_OFF + col])) + lb[2 * HID + col]);
  float c;
  if (hasC) {
    float fg = sigmoidf_(b2f(__builtin_nontemporal_load(&g[F_OFF + col])) + lb[HID + col]);
    c = fg * b2f(cin16[row * ldc16 + col]) + ig * gg;
  } else {
    c = ig * gg;
  }
  cout16[row * ld16 + col] = f2b(c);
}

// ---------------- LSTM cell part 2: hy16 = sigma(gates_O + obuf + b_o)*tanh(c) ---
__global__ __launch_bounds__(256) void cell2_k(
    const unsigned short* __restrict__ gates, const unsigned short* __restrict__ obuf16,
    const float* __restrict__ lb, const unsigned short* __restrict__ cy16, int ldcy,
    unsigned short* __restrict__ hy16, int ld16, int rows)
{
  size_t gid = (size_t)blockIdx.x * 256 + threadIdx.x;
  if (gid >= (size_t)rows * HID) return;
  size_t row = gid >> 9;
  int    col = (int)(gid & (HID - 1));
  float ov = b2f(__builtin_nontemporal_load(&gates[row * G4 + O_OFF + col]));
  float og = sigmoidf_(ov + b2f(obuf16[row * HID + col]) + lb[3 * HID + col]);
  float h = og * tanhf(b2f(cy16[row * ldcy + col]));
  hy16[row * ld16 + col] = f2b(h);
}

// ---------------- fused final cell2 + output projection ----------------
__global__ __launch_bounds__(256) void cellout_k(
    const unsigned short* __restrict__ gates, const unsigned short* __restrict__ obuf16,
    const float* __restrict__ lb, const unsigned short* __restrict__ cy16, int ldcy,
    const float* __restrict__ W, const float* __restrict__ b,
    float* __restrict__ out, int rows)
{
  int wave = (int)(((size_t)blockIdx.x * 256 + threadIdx.x) >> 6);
  int lane = threadIdx.x & 63;
  if (wave >= rows) return;
  const unsigned short* g  = &gates[(size_t)wave * G4 + O_OFF];
  const unsigned short* ob = &obuf16[(size_t)wave * HID];
  const unsigned short* cr = &cy16[(size_t)wave * ldcy];
  float hy[8];
  #pragma unroll
  for (int j = 0; j < 8; j++) {
    int k = lane + j * 64;
    float og = sigmoidf_(b2f(__builtin_nontemporal_load(&g[k])) + b2f(ob[k]) + lb[3 * HID + k]);
    hy[j] = og * tanhf(b2f(cr[k]));
  }
  float acc[12] = {};
  #pragma unroll
  for (int j = 0; j < 8; j++) {
    int k = lane + j * 64;
    const float* wr = &W[k * 12];
    #pragma unroll
    for (int p = 0; p < 12; p++) acc[p] = fmaf(hy[j], wr[p], acc[p]);
  }
  #pragma unroll
  for (int p = 0; p < 12; p++) {
    float v = acc[p];
    #pragma unroll
    for (int off = 32; off > 0; off >>= 1) v += __shfl_down(v, off);
    if (lane == 0) out[(size_t)wave * 12 + p] = v + b[p];
  }
}

extern "C" void kernel_launch(void* const* d_in, const int* in_sizes, int n_in,
                              void* d_out, int out_size, void* d_ws, size_t ws_size,
                              hipStream_t stream) {
  const float* x     = (const float*)d_in[0];
  const int*   ei    = (const int*)d_in[1];
  const float* ew    = (const float*)d_in[2];
  const float* gcn0W = (const float*)d_in[3];
  const float* gcnW  = (const float*)d_in[5];
  const float* gamma = (const float*)d_in[7];
  const float* beta  = (const float*)d_in[8];
  const float* wih   = (const float*)d_in[9];
  const float* whh   = (const float*)d_in[10];
  const float* wch   = (const float*)d_in[11];
  const float* lstmb = (const float*)d_in[12];
  const float* outW  = (const float*)d_in[13];
  const float* outb  = (const float*)d_in[14];
  float* out = (float*)d_out;

  const int* src = ei;
  const int* dst = ei + N_EDGES;

  // R12: gates are bf16 -> half the bytes per row -> CH doubles within the
  // SAME workspace region the fp32 layout used (byte-exact fit).
  const int CHL = (ws_size >= (size_t)215000000) ? 10000 : 5000;  // layout unit
  const int CH  = 2 * CHL;
  const int NCHUNK = N_NODES / CH;

  // -------- workspace layout (byte offsets identical to R11) --------
  const size_t NH = (size_t)N_NODES * HID;
  float* ws = (float*)d_ws;
  float* gates = ws;                                 // CHL*2048 fp32 bytes = CH*2048 bf16
  float* bufH  = gates + (size_t)CHL * G4;           // NH fp32 (GCN H / LSTM a16)
  unsigned short* hbA16 = (unsigned short*)(bufH + NH);
  unsigned short* hbB16 = hbA16 + NH;                // GCN scratch / LSTM obuf16
  unsigned short* x16   = hbB16 + NH;                // scratch (scan block sums)
  unsigned short* g0t   = x16 + (size_t)N_NODES * IN_CH;
  unsigned short* g1t   = g0t   + 512 * 64;
  unsigned short* g2t   = g1t   + 512 * 512;
  unsigned short* wih0t = g2t   + 512 * 512;             // [1536,512] rows g|i|o
  unsigned short* wcat3 = wih0t + (size_t)1536 * 512;    // [2048,1536] fused L1 B
  unsigned short* wch0ot= wcat3 + (size_t)2048 * 1536;   // [512,512]
  unsigned short* wch1ot= wch0ot + 512 * 512;            // [512,512]
  unsigned short* wend  = wch1ot + 512 * 512;
  float* stats = (float*)wend;                       // 3 layers x 1024 floats
  int*   csr   = (int*)(stats + 3072);
  int*   counts  = csr;
  int*   offsets = csr + 20032;
  int*   cpos    = csr + 40064;
  int*   s_s     = csr + 60096;
  float* w_s     = (float*)(csr + 380096);
  int*   bsum    = (int*)x16;                        // 157 ints, prologue-only

  unsigned short* bufH16 = (unsigned short*)bufH;  // bf16 H during GCN
  // LSTM-phase buffers (GCN scratch reused; no temporal overlap):
  unsigned short* gates16 = (unsigned short*)gates;  // bf16 [CH, G4]
  unsigned short* a16     = (unsigned short*)bufH;   // bf16 [CH,1024] = [hy | c]
  unsigned short* obuf16  = hbB16;                   // bf16 [CH,512] o-peephole

  const dim3 blk(256);
  // Wide-N gates GEMM (NC=1536/2048, variable-K split-A), bf16 out, nt.
  auto gemm128 = [&](const unsigned short* A, int lda,
                     const unsigned short* A2, int lda2, int ksplit,
                     const unsigned short* Bt, unsigned short* C16,
                     int M, int K, int Ksmall, int NC, int ldc) {
    int nrowb = (M + 63) / 64;
    int ncolb = NC / 128;
    int nblocks = 8 * ((nrowb + 7) / 8) * ncolb;
    hipLaunchKernelGGL((gemm_bf16_k<64, 128>), dim3(nblocks), blk, 0, stream,
                       A, lda, A2, lda2, ksplit, Bt, (float*)nullptr, C16,
                       (const float*)nullptr,
                       M, K, Ksmall, NC, ldc, 0, /*ntc=*/1, nrowb, ncolb);
  };
  // R15: all NC=512 GEMMs also use <64,128> (ncolb=4 vs the old <128,64>'s
  // 8 -> halves A-panel re-reads; same 48KB/3blk-CU occupancy).
  auto gemmH = [&](const unsigned short* A, int lda,
                   const unsigned short* Bt, float* C, unsigned short* C16,
                   const float* bias, int M, int K, int NC, int ldc, int acc,
                   int ntc) {
    int nrowb = (M + 63) / 64;
    int ncolb = NC / 128;
    int nblocks = 8 * ((nrowb + 7) / 8) * ncolb;
    hipLaunchKernelGGL((gemm_bf16_k<64, 128>), dim3(nblocks), blk, 0, stream,
                       A, lda, A, lda, K, Bt, C, C16, bias,
                       M, K, K, NC, ldc, acc, ntc, nrowb, ncolb);
  };
  auto zero = [&](float* p, size_t n) {
    hipLaunchKernelGGL(zero_k, dim3((unsigned)((n / 4 + 255) / 256)), blk, 0, stream, p, n);
  };

  // -------- weight prep: all 18 transposes in ONE launch --------
  const float* wih1 = wih + (size_t)HID * G4;
  const float* whh1 = whh + (size_t)HID * G4;
  const float* wch1 = wch + (size_t)HID * 3 * HID;
  {
    TcvtBatch tb;
    int n = 0;
    auto add = [&](const float* W, unsigned short* Wt, int K, int NC, int ldw, int ldo) {
      tb.d[n++] = TcvtDesc{W, Wt, K, NC, ldw, ldo};
    };
    add(gcn0W, g0t, IN_CH, HID, HID, IN_CH);
    add(gcnW,                     g1t, HID, HID, HID, HID);
    add(gcnW + (size_t)HID * HID, g2t, HID, HID, HID, HID);
    // layer-0 Wih rows [g|i|o] (f dead: c=0)
    add(wih + 2 * HID, wih0t,                      HID, HID, G4, HID);  // g
    add(wih,           wih0t + (size_t)512 * 512,  HID, HID, G4, HID);  // i
    add(wih + 3 * HID, wih0t + (size_t)1024 * 512, HID, HID, G4, HID);  // o
    // fused layer-1 B [2048 x 1536]: rows f,g K=1536 (ih|hh|peep); i,o K=1024
    add(wih1 + HID,     wcat3 + (size_t)F_OFF * 1536,        HID, HID, G4, 1536);
    add(whh1 + HID,     wcat3 + (size_t)F_OFF * 1536 + 512,  HID, HID, G4, 1536);
    add(wch1 + HID,     wcat3 + (size_t)F_OFF * 1536 + 1024, HID, HID, 3 * HID, 1536);
    add(wih1 + 2 * HID, wcat3 + (size_t)G_OFF * 1536,        HID, HID, G4, 1536);
    add(whh1 + 2 * HID, wcat3 + (size_t)G_OFF * 1536 + 512,  HID, HID, G4, 1536);
    add(wch1,           wcat3 + (size_t)G_OFF * 1536 + 1024, HID, HID, 3 * HID, 1536);
    add(wih1,           wcat3 + (size_t)I_OFF * 1536,        HID, HID, G4, 1536);
    add(whh1,           wcat3 + (size_t)I_OFF * 1536 + 512,  HID, HID, G4, 1536);
    add(wih1 + 3 * HID, wcat3 + (size_t)O_OFF * 1536,        HID, HID, G4, 1536);
    add(whh1 + 3 * HID, wcat3 + (size_t)O_OFF * 1536 + 512,  HID, HID, G4, 1536);
    add(wch + 2 * HID,  wch0ot, HID, HID, 3 * HID, HID);   // Wch0 o-peephole
    add(wch1 + 2 * HID, wch1ot, HID, HID, 3 * HID, HID);   // Wch1 o-peephole
    hipLaunchKernelGGL(tcvtb_k, dim3(16, 16, 18), dim3(32, 8), 0, stream, tb);
  }

  // -------- CSR build; stats+counts zeroed in ONE launch (contiguous) --------
  const int e_blocks = (N_EDGES + 255) / 256;
  const int nscanb = (N_NODES + 127) / 128;   // 157
  zero(stats, 3 * 1024 + N_NODES);            // covers stats AND counts
  hipLaunchKernelGGL(hist_k, dim3(e_blocks), blk, 0, stream, dst, counts);
  hipLaunchKernelGGL(scan1_k, dim3(nscanb), dim3(128), 0, stream,
                     counts, offsets, bsum, N_NODES);
  hipLaunchKernelGGL(scan2_k, dim3(nscanb), dim3(128), 0, stream,
                     bsum, offsets, cpos, N_NODES, nscanb);
  hipLaunchKernelGGL(fill_k, dim3(e_blocks), blk, 0, stream, src, dst, ew, cpos, s_s, w_s);

  // -------- GCN layer 0: gather-first (linearity), direct f32 input --------
  hipLaunchKernelGGL(gather64_k, dim3(N_NODES / 4), dim3(64), 0, stream,
                     x, offsets, s_s, w_s, hbB16);
  gemmH(hbB16, IN_CH, g0t, nullptr, bufH16, nullptr, N_NODES, IN_CH, HID, HID, 0, 0);
  hipLaunchKernelGGL(bn_stats_k, dim3(8, 64), blk, 0, stream, bufH16, stats, N_NODES);
  hipLaunchKernelGGL(bn_apply_k, dim3((unsigned)(NH / 4 / 256)), blk, 0, stream,
                     bufH16, stats, gamma, beta, hbA16, N_NODES);

  // -------- GCN layers 1,2: GEMM -> gather -> BN stats -> BN apply --------
  // (XW outputs NOT nt: gather re-reads each row ~16x, wants them cached.)
  const unsigned short* gWt2[2] = {g1t, g2t};
  const unsigned short* gA2[2]  = {hbA16, hbB16};
  unsigned short*       gXW2[2] = {hbB16, hbA16};
  unsigned short*       gO2[2]  = {hbB16, hbA16};
  for (int l = 0; l < 2; l++) {
    gemmH(gA2[l], HID, gWt2[l], nullptr, gXW2[l], nullptr, N_NODES, HID, HID, HID, 0, 0);
    hipLaunchKernelGGL(gather_k, dim3(N_NODES), dim3(128), 0, stream,
                       gXW2[l], offsets, s_s, w_s, bufH16);
    hipLaunchKernelGGL(bn_stats_k, dim3(8, 64), blk, 0, stream, bufH16,
                       stats + (l + 1) * 1024, N_NODES);
    hipLaunchKernelGGL(bn_apply_k, dim3((unsigned)(NH / 4 / 256)), blk, 0, stream,
                       bufH16, stats + (l + 1) * 1024, gamma + (l + 1) * HID,
                       beta + (l + 1) * HID, gO2[l], N_NODES);
  }
  unsigned short* hfin16 = hbA16;
  // After GCN: hbB16 (layer-1 h) and bufH (pre-BN H) are dead -> reuse as
  // obuf16 and a16 for the LSTM phase. hfin16=hbA16 preserved.

  // -------- LSTM + output, chunked (CH doubled vs R11; often NCHUNK=1) ------
  for (int ci = 0; ci < NCHUNK; ci++) {
    const int r0 = ci * CH;
    const unsigned short* h_c = hfin16 + (size_t)r0 * HID;
    const int cell_blocks = (int)(((size_t)CH * HID + 255) / 256);

    // layer 0 (h=c=0, f dead): gates16[G|I|O] = bf16(h @ Wih0_gio), nt stores
    gemm128(h_c, HID, h_c, HID, HID, wih0t, gates16 + G_OFF,
            CH, HID, HID, 1536, G4);
    // c0 -> a16[:,512:] bf16
    hipLaunchKernelGGL(cell1_k, dim3(cell_blocks), blk, 0, stream,
                       gates16, lstmb, (const unsigned short*)nullptr, 0,
                       a16 + 512, 1024, CH, 0);
    // o peephole L0: obuf16 = bf16(c0 @ Wch0_o), nt (read-once by cell2)
    gemmH(a16 + 512, 1024, wch0ot, nullptr, obuf16, nullptr, CH, HID, HID, HID, 0, 1);
    // hy0 -> a16[:,0:512] bf16
    hipLaunchKernelGGL(cell2_k, dim3(cell_blocks), blk, 0, stream,
                       gates16, obuf16, lstmb, a16 + 512, 1024, a16, 1024, CH);

    // layer 1 fused: gates16 = bf16([h | hy0 | c0] @ wcat3) (split-A;
    // f,g K=1536, i,o K=1024), nt stores
    gemm128(h_c, HID, a16, 1024, HID, wcat3, gates16,
            CH, 1536, 1024, G4, G4);
    // c1 -> a16[:,512:] (reads c0 from same slot elementwise-before-write)
    hipLaunchKernelGGL(cell1_k, dim3(cell_blocks), blk, 0, stream,
                       gates16, lstmb + G4, a16 + 512, 1024,
                       a16 + 512, 1024, CH, 1);
    // o peephole L1: obuf16 = bf16(c1 @ Wch1_o), nt (read-once by cellout)
    gemmH(a16 + 512, 1024, wch1ot, nullptr, obuf16, nullptr, CH, HID, HID, HID, 0, 1);
    // fused cell2 + output projection
    hipLaunchKernelGGL(cellout_k, dim3((CH * 64 + 255) / 256), blk, 0, stream,
                       gates16, obuf16, lstmb + G4, a16 + 512, 1024, outW, outb,
                       out + (size_t)r0 * 12, CH);
  }
}